// Round 12
// baseline (255.890 us; speedup 1.0000x reference)
//
#include <hip/hip_runtime.h>
#include <hip/hip_bf16.h>

#define B_SZ   2
#define LSEQ   4096
#define NCH    512
#define CL     8
#define DROWS  16

typedef __attribute__((ext_vector_type(8))) short short8;
typedef __attribute__((ext_vector_type(4))) float f32x4;

__device__ __forceinline__ unsigned short f2bf(float f) {
  union { float f; unsigned u; } x; x.f = f;
  unsigned r = x.u + 0x7fffu + ((x.u >> 16) & 1u);
  return (unsigned short)(r >> 16);
}
__device__ __forceinline__ float bf2f(unsigned short u) {
  union { unsigned u; float f; } x; x.u = (unsigned)u << 16;
  return x.f;
}

// global->LDS direct async copy, 16B per lane; l must be wave-uniform base.
__device__ __forceinline__ void gload_lds16(const unsigned short* g, unsigned short* l) {
  __builtin_amdgcn_global_load_lds(
      (const __attribute__((address_space(1))) unsigned int*)g,
      (__attribute__((address_space(3))) unsigned int*)l, 16, 0, 0);
}

// ---- prep: LN1 (blocks 0..2047) + weight converts + Ar table (blocks 2048+) ----
__global__ __launch_bounds__(256) void prep_kernel(
    const float* __restrict__ x, const float* __restrict__ ln_w,
    const float* __restrict__ ln_b, unsigned short* __restrict__ xn_bf,
    const float* __restrict__ inW,  unsigned short* __restrict__ inW_bf,
    const float* __restrict__ outW, unsigned short* __restrict__ outW_bf,
    const float* __restrict__ projW, unsigned short* __restrict__ projW_bf,
    const float* __restrict__ xprojW, unsigned short* __restrict__ xprojW_bf,
    const float* __restrict__ A_log, float* __restrict__ Ar_tab)
{
  if (blockIdx.x < 2048) {
    int wv = threadIdx.x >> 6, lane = threadIdx.x & 63;
    size_t row = (size_t)blockIdx.x * 4 + wv;
    float4 v = reinterpret_cast<const float4*>(x)[row * 64 + lane];
    float s  = v.x + v.y + v.z + v.w;
    float sq = v.x*v.x + v.y*v.y + v.z*v.z + v.w*v.w;
    #pragma unroll
    for (int off = 32; off; off >>= 1) {
      s  += __shfl_xor(s,  off);
      sq += __shfl_xor(sq, off);
    }
    float mu  = s * (1.f/256.f);
    float var = sq * (1.f/256.f) - mu*mu;
    float rs  = rsqrtf(var + 1e-5f);
    float4 wv4 = reinterpret_cast<const float4*>(ln_w)[lane];
    float4 bv4 = reinterpret_cast<const float4*>(ln_b)[lane];
    ushort4 o;
    o.x = f2bf((v.x-mu)*rs*wv4.x + bv4.x);
    o.y = f2bf((v.y-mu)*rs*wv4.y + bv4.y);
    o.z = f2bf((v.z-mu)*rs*wv4.z + bv4.z);
    o.w = f2bf((v.w-mu)*rs*wv4.w + bv4.w);
    reinterpret_cast<ushort4*>(xn_bf)[row * 64 + lane] = o;
    return;
  }
  int j = (blockIdx.x - 2048) * 256 + threadIdx.x;
  const float* src; unsigned short* dst; int off;
  if (j < 65536)       { src = inW;    dst = inW_bf;    off = j; }
  else if (j < 98304)  { src = outW;   dst = outW_bf;   off = j - 65536; }
  else if (j < 114688) { src = projW;  dst = projW_bf;  off = j - 98304; }
  else if (j < 120832) { src = xprojW; dst = xprojW_bf; off = j - 114688; }
  else {
    int a = (j - 120832) * 4;
    float4 v = *reinterpret_cast<const float4*>(A_log + a);
    float4 o = {-__expf(v.x), -__expf(v.y), -__expf(v.z), -__expf(v.w)};
    *reinterpret_cast<float4*>(Ar_tab + a) = o;
    return;
  }
  float4 v = *reinterpret_cast<const float4*>(src + off*4);
  ushort4 o;
  o.x = f2bf(v.x); o.y = f2bf(v.y); o.z = f2bf(v.z); o.w = f2bf(v.w);
  *reinterpret_cast<ushort4*>(dst + off*4) = o;
}

// ---------------- LN2: bf16 in, bf16 out ------------------------------------
__global__ __launch_bounds__(256) void ln_bf16_kernel(
    const unsigned short* __restrict__ in, const float* __restrict__ w,
    const float* __restrict__ b, unsigned short* __restrict__ out)
{
  int wv = threadIdx.x >> 6, lane = threadIdx.x & 63;
  size_t row = (size_t)blockIdx.x * 4 + wv;
  ushort4 uv = reinterpret_cast<const ushort4*>(in)[row * 64 + lane];
  float4 v = {bf2f(uv.x), bf2f(uv.y), bf2f(uv.z), bf2f(uv.w)};
  float s  = v.x + v.y + v.z + v.w;
  float sq = v.x*v.x + v.y*v.y + v.z*v.z + v.w*v.w;
  #pragma unroll
  for (int off = 32; off; off >>= 1) {
    s  += __shfl_xor(s,  off);
    sq += __shfl_xor(sq, off);
  }
  float mu  = s * (1.f/256.f);
  float var = sq * (1.f/256.f) - mu*mu;
  float rs  = rsqrtf(var + 1e-5f);
  float4 wv4 = reinterpret_cast<const float4*>(w)[lane];
  float4 bv4 = reinterpret_cast<const float4*>(b)[lane];
  ushort4 o;
  o.x = f2bf((v.x-mu)*rs*wv4.x + bv4.x);
  o.y = f2bf((v.y-mu)*rs*wv4.y + bv4.y);
  o.z = f2bf((v.z-mu)*rs*wv4.z + bv4.z);
  o.w = f2bf((v.w-mu)*rs*wv4.w + bv4.w);
  reinterpret_cast<ushort4*>(out)[row * 64 + lane] = o;
}

// ------ bf16 MFMA GEMM, global_load_lds + dbuf pipeline: C = A * W^T --------
enum { EPI_NONE = 0, EPI_SKIPX = 1, EPI_BIAS = 2 };

template<int BM, int BN, int EPI, typename OT>
__global__ __launch_bounds__(256) void gemm_mfma(
    const unsigned short* __restrict__ A, const unsigned short* __restrict__ W,
    OT* __restrict__ C, int M, int N, int K,
    const float* __restrict__ X, const float* __restrict__ sscale,
    const float* __restrict__ bias)
{
  constexpr int BK = 32;
  constexpr int WM = BM / 2, WN = BN / 2;       // 2x2 waves
  constexpr int AM = WM / 16, BF = WN / 16;
  constexpr int AI = BM / 64, BI = BN / 64;     // stage instrs per wave
  __shared__ __align__(16) unsigned short As[2][BM * BK];
  __shared__ __align__(16) unsigned short Ws[2][BN * BK];
  const int tid = threadIdx.x, lane = tid & 63, wid = tid >> 6;
  const int wr = wid >> 1, wc = wid & 1;
  const int bm = blockIdx.x * BM, bn = blockIdx.y * BN;
  const int srow = lane >> 2;          // row within 16-row group
  const int skoff = (lane & 3) * 8;    // bf16 col offset

  f32x4 acc[AM][BF] = {};

  auto stage = [&](int buf, int kt) {
    #pragma unroll
    for (int i = 0; i < AI; i++) {
      int rowg = (wid * AI + i) * 16;
      gload_lds16(A + (size_t)(bm + rowg + srow) * K + kt + skoff,
                  &As[buf][rowg * BK]);
    }
    #pragma unroll
    for (int i = 0; i < BI; i++) {
      int rowg = (wid * BI + i) * 16;
      gload_lds16(W + (size_t)(bn + rowg + srow) * K + kt + skoff,
                  &Ws[buf][rowg * BK]);
    }
  };

  stage(0, 0);
  __syncthreads();
  const int nt = K / BK;
  int cur = 0;
  for (int t = 0; t < nt; t++) {
    if (t + 1 < nt) stage(cur ^ 1, (t + 1) * BK);
    short8 af[AM], bfr[BF];
    #pragma unroll
    for (int i = 0; i < AM; i++)
      af[i] = *reinterpret_cast<const short8*>(
          &As[cur][(wr * WM + i * 16 + (lane & 15)) * BK + (lane >> 4) * 8]);
    #pragma unroll
    for (int j = 0; j < BF; j++)
      bfr[j] = *reinterpret_cast<const short8*>(
          &Ws[cur][(wc * WN + j * 16 + (lane & 15)) * BK + (lane >> 4) * 8]);
    #pragma unroll
    for (int i = 0; i < AM; i++)
      #pragma unroll
      for (int j = 0; j < BF; j++)
        acc[i][j] = __builtin_amdgcn_mfma_f32_16x16x32_bf16(af[i], bfr[j], acc[i][j], 0, 0, 0);
    __syncthreads();
    cur ^= 1;
  }

  float sv = 0.f;
  if constexpr (EPI == EPI_SKIPX) sv = sscale[0];

  #pragma unroll
  for (int i = 0; i < AM; i++) {
    #pragma unroll
    for (int j = 0; j < BF; j++) {
      int row0 = bm + wr * WM + i * 16 + ((lane >> 4) << 2);
      int col  = bn + wc * WN + j * 16 + (lane & 15);
      #pragma unroll
      for (int r = 0; r < 4; r++) {
        float v = acc[i][j][r];
        size_t off = (size_t)(row0 + r) * N + col;
        if constexpr (EPI == EPI_SKIPX) v += sv * X[off];
        if constexpr (EPI == EPI_BIAS)  v += bias[col];
        if constexpr (sizeof(OT) == 2) C[off] = (OT)f2bf(v);
        else                           C[off] = v;
      }
    }
  }
}

// ---------------- x_proj MFMA GEMM: N=48, pipelined -------------------------
__global__ __launch_bounds__(256) void gemm_mfma48(
    const unsigned short* __restrict__ A, const unsigned short* __restrict__ W,
    float* __restrict__ C, int K)
{
  __shared__ __align__(16) unsigned short As[2][64 * 32];
  __shared__ __align__(16) unsigned short Ws[2][48 * 32];
  const int tid = threadIdx.x, lane = tid & 63, wid = tid >> 6;
  const int bm = blockIdx.x * 64;
  const int srow = lane >> 2, skoff = (lane & 3) * 8;

  f32x4 acc[3] = {};

  auto stage = [&](int buf, int kt) {
    int rowg = wid * 16;
    gload_lds16(A + (size_t)(bm + rowg + srow) * K + kt + skoff, &As[buf][rowg * 32]);
    if (wid < 3)
      gload_lds16(W + (size_t)(rowg + srow) * K + kt + skoff, &Ws[buf][rowg * 32]);
  };

  stage(0, 0);
  __syncthreads();
  const int nt = K / 32;
  int cur = 0;
  for (int t = 0; t < nt; t++) {
    if (t + 1 < nt) stage(cur ^ 1, (t + 1) * 32);
    short8 af = *reinterpret_cast<const short8*>(
        &As[cur][(wid * 16 + (lane & 15)) * 32 + (lane >> 4) * 8]);
    #pragma unroll
    for (int j = 0; j < 3; j++) {
      short8 bfr = *reinterpret_cast<const short8*>(
          &Ws[cur][(j * 16 + (lane & 15)) * 32 + (lane >> 4) * 8]);
      acc[j] = __builtin_amdgcn_mfma_f32_16x16x32_bf16(af, bfr, acc[j], 0, 0, 0);
    }
    __syncthreads();
    cur ^= 1;
  }
  int row0 = bm + wid * 16 + ((lane >> 4) << 2);
  #pragma unroll
  for (int j = 0; j < 3; j++) {
    int col = j * 16 + (lane & 15);
    #pragma unroll
    for (int r = 0; r < 4; r++)
      C[(size_t)(row0 + r) * 48 + col] = acc[j][r];
  }
}

// ------ depthwise causal conv (k=4) + SiLU, bf16 in/out ---------------------
__global__ __launch_bounds__(256) void conv_silu_kernel(
    const unsigned short* __restrict__ xz, const float* __restrict__ cw,
    const float* __restrict__ cb, unsigned short* __restrict__ xc_bf)
{
  int idx = blockIdx.x * 256 + threadIdx.x;   // B*L*128
  int d4 = (idx & 127) << 2;
  int bt = idx >> 7;
  int t  = bt & (LSEQ - 1);
  int b  = bt >> 12;
  float a0 = cb[d4], a1 = cb[d4+1], a2 = cb[d4+2], a3 = cb[d4+3];
  float4 w0 = *reinterpret_cast<const float4*>(&cw[(d4+0)*4]);
  float4 w1 = *reinterpret_cast<const float4*>(&cw[(d4+1)*4]);
  float4 w2 = *reinterpret_cast<const float4*>(&cw[(d4+2)*4]);
  float4 w3 = *reinterpret_cast<const float4*>(&cw[(d4+3)*4]);
  const float* wp0 = (const float*)&w0;
  const float* wp1 = (const float*)&w1;
  const float* wp2 = (const float*)&w2;
  const float* wp3 = (const float*)&w3;
  #pragma unroll
  for (int j = 0; j < 4; j++) {
    int tt = t - 3 + j;
    if (tt >= 0) {
      ushort4 xv = *reinterpret_cast<const ushort4*>(&xz[((size_t)b*LSEQ + tt)*1024 + d4]);
      a0 += wp0[j]*bf2f(xv.x); a1 += wp1[j]*bf2f(xv.y);
      a2 += wp2[j]*bf2f(xv.z); a3 += wp3[j]*bf2f(xv.w);
    }
  }
  ushort4 ob;
  ob.x = f2bf(a0 / (1.f + __expf(-a0)));
  ob.y = f2bf(a1 / (1.f + __expf(-a1)));
  ob.z = f2bf(a2 / (1.f + __expf(-a2)));
  ob.w = f2bf(a3 / (1.f + __expf(-a3)));
  *reinterpret_cast<ushort4*>(&xc_bf[((size_t)b*LSEQ + t)*512 + d4]) = ob;
}

// ------ dt_proj v2: weights cached in registers, 16 rows/block, bf16 out ----
__global__ __launch_bounds__(256) void dtproj2_kernel(
    const float* __restrict__ dbc, const float* __restrict__ dpw,
    const float* __restrict__ dpb, unsigned short* __restrict__ delta_bf)
{
  const int tid = threadIdx.x;
  const int d0 = (tid & 127) << 2;
  float4 w[4][4];
  #pragma unroll
  for (int dd = 0; dd < 4; dd++) {
    const float4* wr = reinterpret_cast<const float4*>(&dpw[(d0+dd)*16]);
    w[dd][0] = wr[0]; w[dd][1] = wr[1]; w[dd][2] = wr[2]; w[dd][3] = wr[3];
  }
  float4 bias = *reinterpret_cast<const float4*>(&dpb[d0]);
  const float* bp = (const float*)&bias;
  size_t rbase = (size_t)blockIdx.x * DROWS + (tid >> 7);
  #pragma unroll 2
  for (int rr = 0; rr < DROWS; rr += 2) {
    size_t r = rbase + rr;
    const float4* dt = reinterpret_cast<const float4*>(dbc + r*48);
    float4 t0 = dt[0], t1 = dt[1], t2 = dt[2], t3 = dt[3];
    ushort4 ob;
    unsigned short* obp = (unsigned short*)&ob;
    #pragma unroll
    for (int dd = 0; dd < 4; dd++) {
      float acc = bp[dd];
      acc += t0.x*w[dd][0].x + t0.y*w[dd][0].y + t0.z*w[dd][0].z + t0.w*w[dd][0].w;
      acc += t1.x*w[dd][1].x + t1.y*w[dd][1].y + t1.z*w[dd][1].z + t1.w*w[dd][1].w;
      acc += t2.x*w[dd][2].x + t2.y*w[dd][2].y + t2.z*w[dd][2].z + t2.w*w[dd][2].w;
      acc += t3.x*w[dd][3].x + t3.y*w[dd][3].y + t3.z*w[dd][3].z + t3.w*w[dd][3].w;
      obp[dd] = f2bf(fmaxf(acc, 0.f) + log1pf(__expf(-fabsf(acc))));
    }
    *reinterpret_cast<ushort4*>(&delta_bf[r*512 + d0]) = ob;
  }
}

// ---------------- selective scan, chunked 3-phase, n-split x2, CL=8 ---------
// g bits: [0]=nh, [1..9]=d, [10..18]=c (NCH=512), [19]=b. Block: uniform (b,c).
__global__ __launch_bounds__(256) void scanA_kernel(
    const unsigned short* __restrict__ delta_bf, const unsigned short* __restrict__ xc_bf,
    const float* __restrict__ dbc, const float* __restrict__ Ar_tab,
    unsigned short* __restrict__ hloc, float* __restrict__ Ssum)
{
  __shared__ float Bs[CL][16];
  const int tid = threadIdx.x;
  int g = blockIdx.x * 256 + tid;
  int nh = g & 1;
  int d  = (g >> 1) & 511;
  int c  = (g >> 10) & (NCH - 1);
  int b  = g >> 19;
  size_t tbase = (size_t)b * LSEQ + (size_t)c * CL;
  if (tid < CL * 16)
    Bs[tid >> 4][tid & 15] = dbc[(tbase + (tid >> 4)) * 48 + 16 + (tid & 15)];
  const float4* Ap = reinterpret_cast<const float4*>(Ar_tab + d*16 + nh*8);
  float4 A0 = Ap[0], A1 = Ap[1];
  float Ar[8] = {A0.x, A0.y, A0.z, A0.w, A1.x, A1.y, A1.z, A1.w};
  float h[8] = {};
  float S = 0.f;
  __syncthreads();
  #pragma unroll
  for (int t = 0; t < CL; t++) {
    size_t r = tbase + t;
    float dl = bf2f(delta_bf[r*512 + d]);
    float u  = bf2f(xc_bf[r*512 + d]);
    float du = dl * u;
    S += dl;
    float4 B0 = *reinterpret_cast<const float4*>(&Bs[t][nh*8]);
    float4 B1 = *reinterpret_cast<const float4*>(&Bs[t][nh*8 + 4]);
    float Bv[8] = {B0.x,B0.y,B0.z,B0.w, B1.x,B1.y,B1.z,B1.w};
    #pragma unroll
    for (int n = 0; n < 8; n++)
      h[n] = __expf(dl * Ar[n]) * h[n] + du * Bv[n];
  }
  size_t o = (((size_t)c * B_SZ + b) * 512 + d) * 16 + nh*8;
  short8 hs;
  #pragma unroll
  for (int n = 0; n < 8; n++) hs[n] = (short)f2bf(h[n]);
  *reinterpret_cast<short8*>(&hloc[o]) = hs;
  if (nh == 0) Ssum[((size_t)c * B_SZ + b) * 512 + d] = S;
}

__global__ __launch_bounds__(256) void scanmid2_kernel(
    const unsigned short* __restrict__ hloc, const float* __restrict__ Ssum,
    const float* __restrict__ Ar_tab, unsigned short* __restrict__ henter)
{
  int g = blockIdx.x * 256 + threadIdx.x;   // B*512*16 = 16384
  int n = g & 15, d = (g >> 4) & 511, b = g >> 13;
  float Ar = Ar_tab[d*16 + n];
  float h = 0.f;
  #pragma unroll 4
  for (int c = 0; c < NCH; c++) {
    size_t idx = ((size_t)c * B_SZ + b) * 512 + d;
    henter[idx*16 + n] = f2bf(h);
    h = __expf(Ssum[idx] * Ar) * h + bf2f(hloc[idx*16 + n]);
  }
}

__global__ __launch_bounds__(256) void scanB_kernel(
    const unsigned short* __restrict__ delta_bf, const unsigned short* __restrict__ xc_bf,
    const float* __restrict__ dbc, const float* __restrict__ Ar_tab,
    const unsigned short* __restrict__ henter, const float* __restrict__ Dskip,
    const unsigned short* __restrict__ xz, unsigned short* __restrict__ y_bf)
{
  __shared__ float Bs[CL][16];
  __shared__ float Cs[CL][16];
  const int tid = threadIdx.x;
  int g = blockIdx.x * 256 + tid;
  int nh = g & 1;
  int d  = (g >> 1) & 511;
  int c  = (g >> 10) & (NCH - 1);
  int b  = g >> 19;
  size_t tbase = (size_t)b * LSEQ + (size_t)c * CL;
  if (tid < CL * 16) {
    int ts = tid >> 4, is = tid & 15;
    Bs[ts][is] = dbc[(tbase + ts) * 48 + 16 + is];
  } else if (tid < 2 * CL * 16) {
    int t2 = tid - CL * 16;
    int ts = t2 >> 4, is = t2 & 15;
    Cs[ts][is] = dbc[(tbase + ts) * 48 + 32 + is];
  }
  const float4* Ap = reinterpret_cast<const float4*>(Ar_tab + d*16 + nh*8);
  float4 A0 = Ap[0], A1 = Ap[1];
  float Ar[8] = {A0.x, A0.y, A0.z, A0.w, A1.x, A1.y, A1.z, A1.w};
  size_t o = (((size_t)c * B_SZ + b) * 512 + d) * 16 + nh*8;
  short8 hv = *reinterpret_cast<const short8*>(&henter[o]);
  float h[8];
  #pragma unroll
  for (int n = 0; n < 8; n++) h[n] = bf2f((unsigned short)hv[n]);
  float Dsk = Dskip[d];
  __syncthreads();
  #pragma unroll
  for (int t = 0; t < CL; t++) {
    size_t r = tbase + t;
    float dl = bf2f(delta_bf[r*512 + d]);
    float u  = bf2f(xc_bf[r*512 + d]);
    float du = dl * u;
    float4 B0 = *reinterpret_cast<const float4*>(&Bs[t][nh*8]);
    float4 B1 = *reinterpret_cast<const float4*>(&Bs[t][nh*8 + 4]);
    float4 C0 = *reinterpret_cast<const float4*>(&Cs[t][nh*8]);
    float4 C1 = *reinterpret_cast<const float4*>(&Cs[t][nh*8 + 4]);
    float Bv[8] = {B0.x,B0.y,B0.z,B0.w, B1.x,B1.y,B1.z,B1.w};
    float Cv[8] = {C0.x,C0.y,C0.z,C0.w, C1.x,C1.y,C1.z,C1.w};
    float yp = 0.f;
    #pragma unroll
    for (int n = 0; n < 8; n++) {
      h[n] = __expf(dl * Ar[n]) * h[n] + du * Bv[n];
      yp += h[n] * Cv[n];
    }
    float y = yp + __shfl_xor(yp, 1);
    if (nh == 0) {
      y += u * Dsk;
      float z = bf2f(xz[r*1024 + 512 + d]);
      float sig = 1.f / (1.f + __expf(-z));
      y_bf[r*512 + d] = f2bf(y * z * sig);
    }
  }
}

// ---------------- launch ----------------------------------------------------
extern "C" void kernel_launch(void* const* d_in, const int* in_sizes, int n_in,
                              void* d_out, int out_size, void* d_ws, size_t ws_size,
                              hipStream_t stream)
{
  const float* x      = (const float*)d_in[0];
  const float* ln_w   = (const float*)d_in[1];
  const float* ln_b   = (const float*)d_in[2];
  const float* inW    = (const float*)d_in[3];
  const float* convW  = (const float*)d_in[4];
  const float* convB  = (const float*)d_in[5];
  const float* xprojW = (const float*)d_in[6];
  const float* dtW    = (const float*)d_in[7];
  const float* dtB    = (const float*)d_in[8];
  const float* A_log  = (const float*)d_in[9];
  const float* Dskip  = (const float*)d_in[10];
  const float* outW   = (const float*)d_in[11];
  const float* projW  = (const float*)d_in[12];
  const float* projB  = (const float*)d_in[13];
  const float* skip   = (const float*)d_in[14];
  float* out = (float*)d_out;

  const size_t BL = (size_t)B_SZ * LSEQ;   // 8192
  char* p = (char*)d_ws;
  unsigned short* xn_bf = (unsigned short*)p;  p += BL*256*2;
  unsigned short* xz_bf = (unsigned short*)p;  p += BL*1024*2;
  unsigned short* xc_bf = (unsigned short*)p;  p += BL*512*2;
  float* dbc    = (float*)p;                   p += BL*48*4;
  unsigned short* delta_bf = (unsigned short*)p; p += BL*512*2;
  unsigned short* hloc   = (unsigned short*)p; p += (size_t)NCH*B_SZ*512*16*2;
  unsigned short* henter = (unsigned short*)p; p += (size_t)NCH*B_SZ*512*16*2;
  float* Ssum   = (float*)p;                   p += (size_t)NCH*B_SZ*512*4;
  unsigned short* y_bf = (unsigned short*)p;   p += BL*512*2;
  unsigned short* inW_bf  = (unsigned short*)p; p += 1024*256*2;
  unsigned short* outW_bf = (unsigned short*)p; p += 256*512*2;
  unsigned short* projW_bf= (unsigned short*)p; p += 256*256*2;
  unsigned short* xprojW_bf=(unsigned short*)p; p += 48*512*2;
  float* Ar_tab = (float*)p;                   p += 512*16*4;
  // overlays (disjoint lifetimes):
  unsigned short* xm_bf  = hloc;    // born after scanB (hloc dead after scanmid)
  unsigned short* xn2_bf = xn_bf;   // xn_bf dead after in_proj

  prep_kernel<<<2048 + 480, 256, 0, stream>>>(
      x, ln_w, ln_b, xn_bf, inW, inW_bf, outW, outW_bf,
      projW, projW_bf, xprojW, xprojW_bf, A_log, Ar_tab);

  gemm_mfma<128,128,EPI_NONE><<<dim3(BL/128, 1024/128), 256, 0, stream>>>(
      xn_bf, inW_bf, xz_bf, (int)BL, 1024, 256, nullptr, nullptr, nullptr);

  conv_silu_kernel<<<(B_SZ*LSEQ*128)/256, 256, 0, stream>>>(xz_bf, convW, convB, xc_bf);

  gemm_mfma48<<<BL/64, 256, 0, stream>>>(xc_bf, xprojW_bf, dbc, 512);

  dtproj2_kernel<<<BL/DROWS, 256, 0, stream>>>(dbc, dtW, dtB, delta_bf);

  scanA_kernel<<<(B_SZ*NCH*512*2)/256, 256, 0, stream>>>(
      delta_bf, xc_bf, dbc, Ar_tab, hloc, Ssum);
  scanmid2_kernel<<<B_SZ*512*16/256, 256, 0, stream>>>(hloc, Ssum, Ar_tab, henter);
  scanB_kernel<<<(B_SZ*NCH*512*2)/256, 256, 0, stream>>>(
      delta_bf, xc_bf, dbc, Ar_tab, henter, Dskip, xz_bf, y_bf);

  gemm_mfma<64,64,EPI_SKIPX><<<dim3(BL/64, 256/64), 256, 0, stream>>>(
      y_bf, outW_bf, xm_bf, (int)BL, 256, 512, x, skip, nullptr);

  ln_bf16_kernel<<<BL/4, 256, 0, stream>>>(xm_bf, ln_w, ln_b, xn2_bf);

  gemm_mfma<64,64,EPI_BIAS><<<dim3(BL/64, 256/64), 256, 0, stream>>>(
      xn2_bf, projW_bf, out, (int)BL, 256, 256, nullptr, nullptr, projB);
}

// Round 13
// 218.664 us; speedup vs baseline: 1.1702x; 1.1702x over previous
//
#include <hip/hip_runtime.h>
#include <hip/hip_bf16.h>

#define B_SZ   2
#define LSEQ   4096
#define NCH    512
#define CL     8
#define NG     16
#define GC     (NCH/NG)   // 32
#define DROWS  16

typedef __attribute__((ext_vector_type(8))) short short8;
typedef __attribute__((ext_vector_type(4))) float f32x4;

__device__ __forceinline__ unsigned short f2bf(float f) {
  union { float f; unsigned u; } x; x.f = f;
  unsigned r = x.u + 0x7fffu + ((x.u >> 16) & 1u);
  return (unsigned short)(r >> 16);
}
__device__ __forceinline__ float bf2f(unsigned short u) {
  union { unsigned u; float f; } x; x.u = (unsigned)u << 16;
  return x.f;
}

// global->LDS direct async copy, 16B per lane; l must be wave-uniform base.
__device__ __forceinline__ void gload_lds16(const unsigned short* g, unsigned short* l) {
  __builtin_amdgcn_global_load_lds(
      (const __attribute__((address_space(1))) unsigned int*)g,
      (__attribute__((address_space(3))) unsigned int*)l, 16, 0, 0);
}

// ---- prep: LN1 (blocks 0..2047) + weight converts + Ar table (blocks 2048+) ----
__global__ __launch_bounds__(256) void prep_kernel(
    const float* __restrict__ x, const float* __restrict__ ln_w,
    const float* __restrict__ ln_b, unsigned short* __restrict__ xn_bf,
    const float* __restrict__ inW,  unsigned short* __restrict__ inW_bf,
    const float* __restrict__ outW, unsigned short* __restrict__ outW_bf,
    const float* __restrict__ projW, unsigned short* __restrict__ projW_bf,
    const float* __restrict__ xprojW, unsigned short* __restrict__ xprojW_bf,
    const float* __restrict__ A_log, float* __restrict__ Ar_tab)
{
  if (blockIdx.x < 2048) {
    int wv = threadIdx.x >> 6, lane = threadIdx.x & 63;
    size_t row = (size_t)blockIdx.x * 4 + wv;
    float4 v = reinterpret_cast<const float4*>(x)[row * 64 + lane];
    float s  = v.x + v.y + v.z + v.w;
    float sq = v.x*v.x + v.y*v.y + v.z*v.z + v.w*v.w;
    #pragma unroll
    for (int off = 32; off; off >>= 1) {
      s  += __shfl_xor(s,  off);
      sq += __shfl_xor(sq, off);
    }
    float mu  = s * (1.f/256.f);
    float var = sq * (1.f/256.f) - mu*mu;
    float rs  = rsqrtf(var + 1e-5f);
    float4 wv4 = reinterpret_cast<const float4*>(ln_w)[lane];
    float4 bv4 = reinterpret_cast<const float4*>(ln_b)[lane];
    ushort4 o;
    o.x = f2bf((v.x-mu)*rs*wv4.x + bv4.x);
    o.y = f2bf((v.y-mu)*rs*wv4.y + bv4.y);
    o.z = f2bf((v.z-mu)*rs*wv4.z + bv4.z);
    o.w = f2bf((v.w-mu)*rs*wv4.w + bv4.w);
    reinterpret_cast<ushort4*>(xn_bf)[row * 64 + lane] = o;
    return;
  }
  int j = (blockIdx.x - 2048) * 256 + threadIdx.x;
  const float* src; unsigned short* dst; int off;
  if (j < 65536)       { src = inW;    dst = inW_bf;    off = j; }
  else if (j < 98304)  { src = outW;   dst = outW_bf;   off = j - 65536; }
  else if (j < 114688) { src = projW;  dst = projW_bf;  off = j - 98304; }
  else if (j < 120832) { src = xprojW; dst = xprojW_bf; off = j - 114688; }
  else {
    int a = (j - 120832) * 4;
    float4 v = *reinterpret_cast<const float4*>(A_log + a);
    float4 o = {-__expf(v.x), -__expf(v.y), -__expf(v.z), -__expf(v.w)};
    *reinterpret_cast<float4*>(Ar_tab + a) = o;
    return;
  }
  float4 v = *reinterpret_cast<const float4*>(src + off*4);
  ushort4 o;
  o.x = f2bf(v.x); o.y = f2bf(v.y); o.z = f2bf(v.z); o.w = f2bf(v.w);
  *reinterpret_cast<ushort4*>(dst + off*4) = o;
}

// ---------------- LN2: bf16 in, bf16 out ------------------------------------
__global__ __launch_bounds__(256) void ln_bf16_kernel(
    const unsigned short* __restrict__ in, const float* __restrict__ w,
    const float* __restrict__ b, unsigned short* __restrict__ out)
{
  int wv = threadIdx.x >> 6, lane = threadIdx.x & 63;
  size_t row = (size_t)blockIdx.x * 4 + wv;
  ushort4 uv = reinterpret_cast<const ushort4*>(in)[row * 64 + lane];
  float4 v = {bf2f(uv.x), bf2f(uv.y), bf2f(uv.z), bf2f(uv.w)};
  float s  = v.x + v.y + v.z + v.w;
  float sq = v.x*v.x + v.y*v.y + v.z*v.z + v.w*v.w;
  #pragma unroll
  for (int off = 32; off; off >>= 1) {
    s  += __shfl_xor(s,  off);
    sq += __shfl_xor(sq, off);
  }
  float mu  = s * (1.f/256.f);
  float var = sq * (1.f/256.f) - mu*mu;
  float rs  = rsqrtf(var + 1e-5f);
  float4 wv4 = reinterpret_cast<const float4*>(w)[lane];
  float4 bv4 = reinterpret_cast<const float4*>(b)[lane];
  ushort4 o;
  o.x = f2bf((v.x-mu)*rs*wv4.x + bv4.x);
  o.y = f2bf((v.y-mu)*rs*wv4.y + bv4.y);
  o.z = f2bf((v.z-mu)*rs*wv4.z + bv4.z);
  o.w = f2bf((v.w-mu)*rs*wv4.w + bv4.w);
  reinterpret_cast<ushort4*>(out)[row * 64 + lane] = o;
}

// ------ bf16 MFMA GEMM, global_load_lds + dbuf pipeline: C = A * W^T --------
enum { EPI_NONE = 0, EPI_SKIPX = 1, EPI_BIAS = 2 };

template<int BM, int BN, int EPI, typename OT>
__global__ __launch_bounds__(256) void gemm_mfma(
    const unsigned short* __restrict__ A, const unsigned short* __restrict__ W,
    OT* __restrict__ C, int M, int N, int K,
    const float* __restrict__ X, const float* __restrict__ sscale,
    const float* __restrict__ bias)
{
  constexpr int BK = 32;
  constexpr int WM = BM / 2, WN = BN / 2;       // 2x2 waves
  constexpr int AM = WM / 16, BF = WN / 16;
  constexpr int AI = BM / 64, BI = BN / 64;     // stage instrs per wave
  __shared__ __align__(16) unsigned short As[2][BM * BK];
  __shared__ __align__(16) unsigned short Ws[2][BN * BK];
  const int tid = threadIdx.x, lane = tid & 63, wid = tid >> 6;
  const int wr = wid >> 1, wc = wid & 1;
  const int bm = blockIdx.x * BM, bn = blockIdx.y * BN;
  const int srow = lane >> 2;          // row within 16-row group
  const int skoff = (lane & 3) * 8;    // bf16 col offset

  f32x4 acc[AM][BF] = {};

  auto stage = [&](int buf, int kt) {
    #pragma unroll
    for (int i = 0; i < AI; i++) {
      int rowg = (wid * AI + i) * 16;
      gload_lds16(A + (size_t)(bm + rowg + srow) * K + kt + skoff,
                  &As[buf][rowg * BK]);
    }
    #pragma unroll
    for (int i = 0; i < BI; i++) {
      int rowg = (wid * BI + i) * 16;
      gload_lds16(W + (size_t)(bn + rowg + srow) * K + kt + skoff,
                  &Ws[buf][rowg * BK]);
    }
  };

  stage(0, 0);
  __syncthreads();
  const int nt = K / BK;
  int cur = 0;
  for (int t = 0; t < nt; t++) {
    if (t + 1 < nt) stage(cur ^ 1, (t + 1) * BK);
    short8 af[AM], bfr[BF];
    #pragma unroll
    for (int i = 0; i < AM; i++)
      af[i] = *reinterpret_cast<const short8*>(
          &As[cur][(wr * WM + i * 16 + (lane & 15)) * BK + (lane >> 4) * 8]);
    #pragma unroll
    for (int j = 0; j < BF; j++)
      bfr[j] = *reinterpret_cast<const short8*>(
          &Ws[cur][(wc * WN + j * 16 + (lane & 15)) * BK + (lane >> 4) * 8]);
    #pragma unroll
    for (int i = 0; i < AM; i++)
      #pragma unroll
      for (int j = 0; j < BF; j++)
        acc[i][j] = __builtin_amdgcn_mfma_f32_16x16x32_bf16(af[i], bfr[j], acc[i][j], 0, 0, 0);
    __syncthreads();
    cur ^= 1;
  }

  float sv = 0.f;
  if constexpr (EPI == EPI_SKIPX) sv = sscale[0];

  #pragma unroll
  for (int i = 0; i < AM; i++) {
    #pragma unroll
    for (int j = 0; j < BF; j++) {
      int row0 = bm + wr * WM + i * 16 + ((lane >> 4) << 2);
      int col  = bn + wc * WN + j * 16 + (lane & 15);
      #pragma unroll
      for (int r = 0; r < 4; r++) {
        float v = acc[i][j][r];
        size_t off = (size_t)(row0 + r) * N + col;
        if constexpr (EPI == EPI_SKIPX) v += sv * X[off];
        if constexpr (EPI == EPI_BIAS)  v += bias[col];
        if constexpr (sizeof(OT) == 2) C[off] = (OT)f2bf(v);
        else                           C[off] = v;
      }
    }
  }
}

// ---------------- x_proj MFMA GEMM: N=48, pipelined -------------------------
__global__ __launch_bounds__(256) void gemm_mfma48(
    const unsigned short* __restrict__ A, const unsigned short* __restrict__ W,
    float* __restrict__ C, int K)
{
  __shared__ __align__(16) unsigned short As[2][64 * 32];
  __shared__ __align__(16) unsigned short Ws[2][48 * 32];
  const int tid = threadIdx.x, lane = tid & 63, wid = tid >> 6;
  const int bm = blockIdx.x * 64;
  const int srow = lane >> 2, skoff = (lane & 3) * 8;

  f32x4 acc[3] = {};

  auto stage = [&](int buf, int kt) {
    int rowg = wid * 16;
    gload_lds16(A + (size_t)(bm + rowg + srow) * K + kt + skoff, &As[buf][rowg * 32]);
    if (wid < 3)
      gload_lds16(W + (size_t)(rowg + srow) * K + kt + skoff, &Ws[buf][rowg * 32]);
  };

  stage(0, 0);
  __syncthreads();
  const int nt = K / 32;
  int cur = 0;
  for (int t = 0; t < nt; t++) {
    if (t + 1 < nt) stage(cur ^ 1, (t + 1) * 32);
    short8 af = *reinterpret_cast<const short8*>(
        &As[cur][(wid * 16 + (lane & 15)) * 32 + (lane >> 4) * 8]);
    #pragma unroll
    for (int j = 0; j < 3; j++) {
      short8 bfr = *reinterpret_cast<const short8*>(
          &Ws[cur][(j * 16 + (lane & 15)) * 32 + (lane >> 4) * 8]);
      acc[j] = __builtin_amdgcn_mfma_f32_16x16x32_bf16(af, bfr, acc[j], 0, 0, 0);
    }
    __syncthreads();
    cur ^= 1;
  }
  int row0 = bm + wid * 16 + ((lane >> 4) << 2);
  #pragma unroll
  for (int j = 0; j < 3; j++) {
    int col = j * 16 + (lane & 15);
    #pragma unroll
    for (int r = 0; r < 4; r++)
      C[(size_t)(row0 + r) * 48 + col] = acc[j][r];
  }
}

// ------ depthwise causal conv (k=4) + SiLU, bf16 in/out ---------------------
__global__ __launch_bounds__(256) void conv_silu_kernel(
    const unsigned short* __restrict__ xz, const float* __restrict__ cw,
    const float* __restrict__ cb, unsigned short* __restrict__ xc_bf)
{
  int idx = blockIdx.x * 256 + threadIdx.x;   // B*L*128
  int d4 = (idx & 127) << 2;
  int bt = idx >> 7;
  int t  = bt & (LSEQ - 1);
  int b  = bt >> 12;
  float a0 = cb[d4], a1 = cb[d4+1], a2 = cb[d4+2], a3 = cb[d4+3];
  float4 w0 = *reinterpret_cast<const float4*>(&cw[(d4+0)*4]);
  float4 w1 = *reinterpret_cast<const float4*>(&cw[(d4+1)*4]);
  float4 w2 = *reinterpret_cast<const float4*>(&cw[(d4+2)*4]);
  float4 w3 = *reinterpret_cast<const float4*>(&cw[(d4+3)*4]);
  const float* wp0 = (const float*)&w0;
  const float* wp1 = (const float*)&w1;
  const float* wp2 = (const float*)&w2;
  const float* wp3 = (const float*)&w3;
  #pragma unroll
  for (int j = 0; j < 4; j++) {
    int tt = t - 3 + j;
    if (tt >= 0) {
      ushort4 xv = *reinterpret_cast<const ushort4*>(&xz[((size_t)b*LSEQ + tt)*1024 + d4]);
      a0 += wp0[j]*bf2f(xv.x); a1 += wp1[j]*bf2f(xv.y);
      a2 += wp2[j]*bf2f(xv.z); a3 += wp3[j]*bf2f(xv.w);
    }
  }
  ushort4 ob;
  ob.x = f2bf(a0 / (1.f + __expf(-a0)));
  ob.y = f2bf(a1 / (1.f + __expf(-a1)));
  ob.z = f2bf(a2 / (1.f + __expf(-a2)));
  ob.w = f2bf(a3 / (1.f + __expf(-a3)));
  *reinterpret_cast<ushort4*>(&xc_bf[((size_t)b*LSEQ + t)*512 + d4]) = ob;
}

// ------ dt_proj v2: weights cached in registers, 16 rows/block, bf16 out ----
__global__ __launch_bounds__(256) void dtproj2_kernel(
    const float* __restrict__ dbc, const float* __restrict__ dpw,
    const float* __restrict__ dpb, unsigned short* __restrict__ delta_bf)
{
  const int tid = threadIdx.x;
  const int d0 = (tid & 127) << 2;
  float4 w[4][4];
  #pragma unroll
  for (int dd = 0; dd < 4; dd++) {
    const float4* wr = reinterpret_cast<const float4*>(&dpw[(d0+dd)*16]);
    w[dd][0] = wr[0]; w[dd][1] = wr[1]; w[dd][2] = wr[2]; w[dd][3] = wr[3];
  }
  float4 bias = *reinterpret_cast<const float4*>(&dpb[d0]);
  const float* bp = (const float*)&bias;
  size_t rbase = (size_t)blockIdx.x * DROWS + (tid >> 7);
  #pragma unroll 2
  for (int rr = 0; rr < DROWS; rr += 2) {
    size_t r = rbase + rr;
    const float4* dt = reinterpret_cast<const float4*>(dbc + r*48);
    float4 t0 = dt[0], t1 = dt[1], t2 = dt[2], t3 = dt[3];
    ushort4 ob;
    unsigned short* obp = (unsigned short*)&ob;
    #pragma unroll
    for (int dd = 0; dd < 4; dd++) {
      float acc = bp[dd];
      acc += t0.x*w[dd][0].x + t0.y*w[dd][0].y + t0.z*w[dd][0].z + t0.w*w[dd][0].w;
      acc += t1.x*w[dd][1].x + t1.y*w[dd][1].y + t1.z*w[dd][1].z + t1.w*w[dd][1].w;
      acc += t2.x*w[dd][2].x + t2.y*w[dd][2].y + t2.z*w[dd][2].z + t2.w*w[dd][2].w;
      acc += t3.x*w[dd][3].x + t3.y*w[dd][3].y + t3.z*w[dd][3].z + t3.w*w[dd][3].w;
      obp[dd] = f2bf(fmaxf(acc, 0.f) + log1pf(__expf(-fabsf(acc))));
    }
    *reinterpret_cast<ushort4*>(&delta_bf[r*512 + d0]) = ob;
  }
}

// ---------------- selective scan, chunked 3-phase, n-split x2, CL=8 ---------
__global__ __launch_bounds__(256) void scanA_kernel(
    const unsigned short* __restrict__ delta_bf, const unsigned short* __restrict__ xc_bf,
    const float* __restrict__ dbc, const float* __restrict__ Ar_tab,
    unsigned short* __restrict__ hloc, float* __restrict__ Ssum)
{
  __shared__ float Bs[CL][16];
  const int tid = threadIdx.x;
  int g = blockIdx.x * 256 + tid;
  int nh = g & 1;
  int d  = (g >> 1) & 511;
  int c  = (g >> 10) & (NCH - 1);
  int b  = g >> 19;
  size_t tbase = (size_t)b * LSEQ + (size_t)c * CL;
  if (tid < CL * 16)
    Bs[tid >> 4][tid & 15] = dbc[(tbase + (tid >> 4)) * 48 + 16 + (tid & 15)];
  const float4* Ap = reinterpret_cast<const float4*>(Ar_tab + d*16 + nh*8);
  float4 A0 = Ap[0], A1 = Ap[1];
  float Ar[8] = {A0.x, A0.y, A0.z, A0.w, A1.x, A1.y, A1.z, A1.w};
  float h[8] = {};
  float S = 0.f;
  __syncthreads();
  #pragma unroll
  for (int t = 0; t < CL; t++) {
    size_t r = tbase + t;
    float dl = bf2f(delta_bf[r*512 + d]);
    float u  = bf2f(xc_bf[r*512 + d]);
    float du = dl * u;
    S += dl;
    float4 B0 = *reinterpret_cast<const float4*>(&Bs[t][nh*8]);
    float4 B1 = *reinterpret_cast<const float4*>(&Bs[t][nh*8 + 4]);
    float Bv[8] = {B0.x,B0.y,B0.z,B0.w, B1.x,B1.y,B1.z,B1.w};
    #pragma unroll
    for (int n = 0; n < 8; n++)
      h[n] = __expf(dl * Ar[n]) * h[n] + du * Bv[n];
  }
  size_t o = (((size_t)c * B_SZ + b) * 512 + d) * 16 + nh*8;
  short8 hs;
  #pragma unroll
  for (int n = 0; n < 8; n++) hs[n] = (short)f2bf(h[n]);
  *reinterpret_cast<short8*>(&hloc[o]) = hs;
  if (nh == 0) Ssum[((size_t)c * B_SZ + b) * 512 + d] = S;
}

// ---- hierarchical chunk-combine: NG groups of GC chunks per (b,d,n) --------
// pass 1: per-(b,grp,d,n) group aggregate (E = prod e_c, V = fold)
__global__ __launch_bounds__(256) void scanmidA_kernel(
    const unsigned short* __restrict__ hloc, const float* __restrict__ Ssum,
    const float* __restrict__ Ar_tab, float* __restrict__ Eg, float* __restrict__ Vg)
{
  int blk = blockIdx.x;                 // b*NG*32 + grp*32 + dblk
  int dblk = blk & 31;
  int grp  = (blk >> 5) & (NG - 1);
  int b    = blk >> 9;
  int n  = threadIdx.x & 15, dlo = threadIdx.x >> 4;
  int d  = dblk * 16 + dlo;
  float Ar = Ar_tab[d*16 + n];
  float E = 1.f, V = 0.f;
  #pragma unroll 4
  for (int i = 0; i < GC; i++) {
    int c = grp * GC + i;
    size_t idx = ((size_t)c * B_SZ + b) * 512 + d;
    float Ec = __expf(Ssum[idx] * Ar);
    V = Ec * V + bf2f(hloc[idx*16 + n]);
    E *= Ec;
  }
  size_t o = (size_t)grp * (B_SZ*8192) + (size_t)b * 8192 + d*16 + n;
  Eg[o] = E;
  Vg[o] = V;
}

// pass 2: serial fold over NG groups per (b,d,n) -> group-entry states
__global__ __launch_bounds__(256) void scanmidB_kernel(
    const float* __restrict__ Eg, const float* __restrict__ Vg,
    float* __restrict__ Gent)
{
  int g = blockIdx.x * 256 + threadIdx.x;   // B*8192 = 16384
  float h = 0.f;
  #pragma unroll
  for (int grp = 0; grp < NG; grp++) {
    size_t o = (size_t)grp * (B_SZ*8192) + g;
    Gent[o] = h;
    h = Eg[o] * h + Vg[o];
  }
}

// pass 3: re-walk own group, writing per-chunk entry states (bf16)
__global__ __launch_bounds__(256) void scanmidC_kernel(
    const unsigned short* __restrict__ hloc, const float* __restrict__ Ssum,
    const float* __restrict__ Ar_tab, const float* __restrict__ Gent,
    unsigned short* __restrict__ henter)
{
  int blk = blockIdx.x;
  int dblk = blk & 31;
  int grp  = (blk >> 5) & (NG - 1);
  int b    = blk >> 9;
  int n  = threadIdx.x & 15, dlo = threadIdx.x >> 4;
  int d  = dblk * 16 + dlo;
  float Ar = Ar_tab[d*16 + n];
  float h = Gent[(size_t)grp * (B_SZ*8192) + (size_t)b * 8192 + d*16 + n];
  #pragma unroll 4
  for (int i = 0; i < GC; i++) {
    int c = grp * GC + i;
    size_t idx = ((size_t)c * B_SZ + b) * 512 + d;
    henter[idx*16 + n] = f2bf(h);
    h = __expf(Ssum[idx] * Ar) * h + bf2f(hloc[idx*16 + n]);
  }
}

__global__ __launch_bounds__(256) void scanB_kernel(
    const unsigned short* __restrict__ delta_bf, const unsigned short* __restrict__ xc_bf,
    const float* __restrict__ dbc, const float* __restrict__ Ar_tab,
    const unsigned short* __restrict__ henter, const float* __restrict__ Dskip,
    const unsigned short* __restrict__ xz, unsigned short* __restrict__ y_bf)
{
  __shared__ float Bs[CL][16];
  __shared__ float Cs[CL][16];
  const int tid = threadIdx.x;
  int g = blockIdx.x * 256 + tid;
  int nh = g & 1;
  int d  = (g >> 1) & 511;
  int c  = (g >> 10) & (NCH - 1);
  int b  = g >> 19;
  size_t tbase = (size_t)b * LSEQ + (size_t)c * CL;
  if (tid < CL * 16) {
    int ts = tid >> 4, is = tid & 15;
    Bs[ts][is] = dbc[(tbase + ts) * 48 + 16 + is];
  } else if (tid < 2 * CL * 16) {
    int t2 = tid - CL * 16;
    int ts = t2 >> 4, is = t2 & 15;
    Cs[ts][is] = dbc[(tbase + ts) * 48 + 32 + is];
  }
  const float4* Ap = reinterpret_cast<const float4*>(Ar_tab + d*16 + nh*8);
  float4 A0 = Ap[0], A1 = Ap[1];
  float Ar[8] = {A0.x, A0.y, A0.z, A0.w, A1.x, A1.y, A1.z, A1.w};
  size_t o = (((size_t)c * B_SZ + b) * 512 + d) * 16 + nh*8;
  short8 hv = *reinterpret_cast<const short8*>(&henter[o]);
  float h[8];
  #pragma unroll
  for (int n = 0; n < 8; n++) h[n] = bf2f((unsigned short)hv[n]);
  float Dsk = Dskip[d];
  __syncthreads();
  #pragma unroll
  for (int t = 0; t < CL; t++) {
    size_t r = tbase + t;
    float dl = bf2f(delta_bf[r*512 + d]);
    float u  = bf2f(xc_bf[r*512 + d]);
    float du = dl * u;
    float4 B0 = *reinterpret_cast<const float4*>(&Bs[t][nh*8]);
    float4 B1 = *reinterpret_cast<const float4*>(&Bs[t][nh*8 + 4]);
    float4 C0 = *reinterpret_cast<const float4*>(&Cs[t][nh*8]);
    float4 C1 = *reinterpret_cast<const float4*>(&Cs[t][nh*8 + 4]);
    float Bv[8] = {B0.x,B0.y,B0.z,B0.w, B1.x,B1.y,B1.z,B1.w};
    float Cv[8] = {C0.x,C0.y,C0.z,C0.w, C1.x,C1.y,C1.z,C1.w};
    float yp = 0.f;
    #pragma unroll
    for (int n = 0; n < 8; n++) {
      h[n] = __expf(dl * Ar[n]) * h[n] + du * Bv[n];
      yp += h[n] * Cv[n];
    }
    float y = yp + __shfl_xor(yp, 1);
    if (nh == 0) {
      y += u * Dsk;
      float z = bf2f(xz[r*1024 + 512 + d]);
      float sig = 1.f / (1.f + __expf(-z));
      y_bf[r*512 + d] = f2bf(y * z * sig);
    }
  }
}

// ---------------- launch ----------------------------------------------------
extern "C" void kernel_launch(void* const* d_in, const int* in_sizes, int n_in,
                              void* d_out, int out_size, void* d_ws, size_t ws_size,
                              hipStream_t stream)
{
  const float* x      = (const float*)d_in[0];
  const float* ln_w   = (const float*)d_in[1];
  const float* ln_b   = (const float*)d_in[2];
  const float* inW    = (const float*)d_in[3];
  const float* convW  = (const float*)d_in[4];
  const float* convB  = (const float*)d_in[5];
  const float* xprojW = (const float*)d_in[6];
  const float* dtW    = (const float*)d_in[7];
  const float* dtB    = (const float*)d_in[8];
  const float* A_log  = (const float*)d_in[9];
  const float* Dskip  = (const float*)d_in[10];
  const float* outW   = (const float*)d_in[11];
  const float* projW  = (const float*)d_in[12];
  const float* projB  = (const float*)d_in[13];
  const float* skip   = (const float*)d_in[14];
  float* out = (float*)d_out;

  const size_t BL = (size_t)B_SZ * LSEQ;   // 8192
  char* p = (char*)d_ws;
  unsigned short* xn_bf = (unsigned short*)p;  p += BL*256*2;
  unsigned short* xz_bf = (unsigned short*)p;  p += BL*1024*2;
  unsigned short* xc_bf = (unsigned short*)p;  p += BL*512*2;
  float* dbc    = (float*)p;                   p += BL*48*4;
  unsigned short* delta_bf = (unsigned short*)p; p += BL*512*2;
  unsigned short* hloc   = (unsigned short*)p; p += (size_t)NCH*B_SZ*512*16*2;
  unsigned short* henter = (unsigned short*)p; p += (size_t)NCH*B_SZ*512*16*2;
  float* Ssum   = (float*)p;                   p += (size_t)NCH*B_SZ*512*4;
  unsigned short* y_bf = (unsigned short*)p;   p += BL*512*2;
  unsigned short* inW_bf  = (unsigned short*)p; p += 1024*256*2;
  unsigned short* outW_bf = (unsigned short*)p; p += 256*512*2;
  unsigned short* projW_bf= (unsigned short*)p; p += 256*256*2;
  unsigned short* xprojW_bf=(unsigned short*)p; p += 48*512*2;
  float* Ar_tab = (float*)p;                   p += 512*16*4;
  float* Eg     = (float*)p;                   p += (size_t)NG*B_SZ*8192*4;
  float* Vg     = (float*)p;                   p += (size_t)NG*B_SZ*8192*4;
  float* Gent   = (float*)p;                   p += (size_t)NG*B_SZ*8192*4;
  // overlays (disjoint lifetimes):
  unsigned short* xm_bf  = hloc;    // born after scanB (hloc dead after scanmidC)
  unsigned short* xn2_bf = xn_bf;   // xn_bf dead after in_proj

  prep_kernel<<<2048 + 480, 256, 0, stream>>>(
      x, ln_w, ln_b, xn_bf, inW, inW_bf, outW, outW_bf,
      projW, projW_bf, xprojW, xprojW_bf, A_log, Ar_tab);

  gemm_mfma<128,128,EPI_NONE><<<dim3(BL/128, 1024/128), 256, 0, stream>>>(
      xn_bf, inW_bf, xz_bf, (int)BL, 1024, 256, nullptr, nullptr, nullptr);

  conv_silu_kernel<<<(B_SZ*LSEQ*128)/256, 256, 0, stream>>>(xz_bf, convW, convB, xc_bf);

  gemm_mfma48<<<BL/64, 256, 0, stream>>>(xc_bf, xprojW_bf, dbc, 512);

  dtproj2_kernel<<<BL/DROWS, 256, 0, stream>>>(dbc, dtW, dtB, delta_bf);

  scanA_kernel<<<(B_SZ*NCH*512*2)/256, 256, 0, stream>>>(
      delta_bf, xc_bf, dbc, Ar_tab, hloc, Ssum);
  scanmidA_kernel<<<B_SZ*NG*32, 256, 0, stream>>>(hloc, Ssum, Ar_tab, Eg, Vg);
  scanmidB_kernel<<<B_SZ*8192/256, 256, 0, stream>>>(Eg, Vg, Gent);
  scanmidC_kernel<<<B_SZ*NG*32, 256, 0, stream>>>(hloc, Ssum, Ar_tab, Gent, henter);
  scanB_kernel<<<(B_SZ*NCH*512*2)/256, 256, 0, stream>>>(
      delta_bf, xc_bf, dbc, Ar_tab, henter, Dskip, xz_bf, y_bf);

  gemm_mfma<64,64,EPI_SKIPX><<<dim3(BL/64, 256/64), 256, 0, stream>>>(
      y_bf, outW_bf, xm_bf, (int)BL, 256, 512, x, skip, nullptr);

  ln_bf16_kernel<<<BL/4, 256, 0, stream>>>(xm_bf, ln_w, ln_b, xn2_bf);

  gemm_mfma<64,64,EPI_BIAS><<<dim3(BL/64, 256/64), 256, 0, stream>>>(
      xn2_bf, projW_bf, out, (int)BL, 256, 256, nullptr, nullptr, projB);
}

// Round 15
// 216.864 us; speedup vs baseline: 1.1800x; 1.0083x over previous
//
#include <hip/hip_runtime.h>
#include <hip/hip_bf16.h>

#define B_SZ   2
#define LSEQ   4096
#define NCH    512
#define CL     8
#define NG     16
#define GC     (NCH/NG)   // 32
#define DROWS  16

typedef __attribute__((ext_vector_type(8))) short short8;
typedef __attribute__((ext_vector_type(4))) float f32x4;

__device__ __forceinline__ unsigned short f2bf(float f) {
  union { float f; unsigned u; } x; x.f = f;
  unsigned r = x.u + 0x7fffu + ((x.u >> 16) & 1u);
  return (unsigned short)(r >> 16);
}
__device__ __forceinline__ float bf2f(unsigned short u) {
  union { unsigned u; float f; } x; x.u = (unsigned)u << 16;
  return x.f;
}

// global->LDS direct async copy, 16B per lane; l must be wave-uniform base.
__device__ __forceinline__ void gload_lds16(const unsigned short* g, unsigned short* l) {
  __builtin_amdgcn_global_load_lds(
      (const __attribute__((address_space(1))) unsigned int*)g,
      (__attribute__((address_space(3))) unsigned int*)l, 16, 0, 0);
}

// ---- prep: LN1 (blocks 0..2047) + weight converts + Ar table (blocks 2048+) ----
__global__ __launch_bounds__(256) void prep_kernel(
    const float* __restrict__ x, const float* __restrict__ ln_w,
    const float* __restrict__ ln_b, unsigned short* __restrict__ xn_bf,
    const float* __restrict__ inW,  unsigned short* __restrict__ inW_bf,
    const float* __restrict__ outW, unsigned short* __restrict__ outW_bf,
    const float* __restrict__ projW, unsigned short* __restrict__ projW_bf,
    const float* __restrict__ xprojW, unsigned short* __restrict__ xprojW_bf,
    const float* __restrict__ A_log, float* __restrict__ Ar_tab)
{
  if (blockIdx.x < 2048) {
    int wv = threadIdx.x >> 6, lane = threadIdx.x & 63;
    size_t row = (size_t)blockIdx.x * 4 + wv;
    float4 v = reinterpret_cast<const float4*>(x)[row * 64 + lane];
    float s  = v.x + v.y + v.z + v.w;
    float sq = v.x*v.x + v.y*v.y + v.z*v.z + v.w*v.w;
    #pragma unroll
    for (int off = 32; off; off >>= 1) {
      s  += __shfl_xor(s,  off);
      sq += __shfl_xor(sq, off);
    }
    float mu  = s * (1.f/256.f);
    float var = sq * (1.f/256.f) - mu*mu;
    float rs  = rsqrtf(var + 1e-5f);
    float4 wv4 = reinterpret_cast<const float4*>(ln_w)[lane];
    float4 bv4 = reinterpret_cast<const float4*>(ln_b)[lane];
    ushort4 o;
    o.x = f2bf((v.x-mu)*rs*wv4.x + bv4.x);
    o.y = f2bf((v.y-mu)*rs*wv4.y + bv4.y);
    o.z = f2bf((v.z-mu)*rs*wv4.z + bv4.z);
    o.w = f2bf((v.w-mu)*rs*wv4.w + bv4.w);
    reinterpret_cast<ushort4*>(xn_bf)[row * 64 + lane] = o;
    return;
  }
  int j = (blockIdx.x - 2048) * 256 + threadIdx.x;
  const float* src; unsigned short* dst; int off;
  if (j < 65536)       { src = inW;    dst = inW_bf;    off = j; }
  else if (j < 98304)  { src = outW;   dst = outW_bf;   off = j - 65536; }
  else if (j < 114688) { src = projW;  dst = projW_bf;  off = j - 98304; }
  else if (j < 120832) { src = xprojW; dst = xprojW_bf; off = j - 114688; }
  else {
    int a = (j - 120832) * 4;
    float4 v = *reinterpret_cast<const float4*>(A_log + a);
    float4 o = {-__expf(v.x), -__expf(v.y), -__expf(v.z), -__expf(v.w)};
    *reinterpret_cast<float4*>(Ar_tab + a) = o;
    return;
  }
  float4 v = *reinterpret_cast<const float4*>(src + off*4);
  ushort4 o;
  o.x = f2bf(v.x); o.y = f2bf(v.y); o.z = f2bf(v.z); o.w = f2bf(v.w);
  *reinterpret_cast<ushort4*>(dst + off*4) = o;
}

// ---------------- LN2: bf16 in, bf16 out ------------------------------------
__global__ __launch_bounds__(256) void ln_bf16_kernel(
    const unsigned short* __restrict__ in, const float* __restrict__ w,
    const float* __restrict__ b, unsigned short* __restrict__ out)
{
  int wv = threadIdx.x >> 6, lane = threadIdx.x & 63;
  size_t row = (size_t)blockIdx.x * 4 + wv;
  ushort4 uv = reinterpret_cast<const ushort4*>(in)[row * 64 + lane];
  float4 v = {bf2f(uv.x), bf2f(uv.y), bf2f(uv.z), bf2f(uv.w)};
  float s  = v.x + v.y + v.z + v.w;
  float sq = v.x*v.x + v.y*v.y + v.z*v.z + v.w*v.w;
  #pragma unroll
  for (int off = 32; off; off >>= 1) {
    s  += __shfl_xor(s,  off);
    sq += __shfl_xor(sq, off);
  }
  float mu  = s * (1.f/256.f);
  float var = sq * (1.f/256.f) - mu*mu;
  float rs  = rsqrtf(var + 1e-5f);
  float4 wv4 = reinterpret_cast<const float4*>(w)[lane];
  float4 bv4 = reinterpret_cast<const float4*>(b)[lane];
  ushort4 o;
  o.x = f2bf((v.x-mu)*rs*wv4.x + bv4.x);
  o.y = f2bf((v.y-mu)*rs*wv4.y + bv4.y);
  o.z = f2bf((v.z-mu)*rs*wv4.z + bv4.z);
  o.w = f2bf((v.w-mu)*rs*wv4.w + bv4.w);
  reinterpret_cast<ushort4*>(out)[row * 64 + lane] = o;
}

// ------ bf16 MFMA GEMM, global_load_lds + dbuf pipeline: C = A * W^T --------
enum { EPI_NONE = 0, EPI_SKIPX = 1, EPI_BIAS = 2 };

template<int BM, int BN, int EPI, typename OT>
__global__ __launch_bounds__(256) void gemm_mfma(
    const unsigned short* __restrict__ A, const unsigned short* __restrict__ W,
    OT* __restrict__ C, int M, int N, int K,
    const float* __restrict__ X, const float* __restrict__ sscale,
    const float* __restrict__ bias)
{
  constexpr int BK = 32;
  constexpr int WM = BM / 2, WN = BN / 2;       // 2x2 waves
  constexpr int AM = WM / 16, BF = WN / 16;
  constexpr int AI = BM / 64, BI = BN / 64;     // stage instrs per wave
  __shared__ __align__(16) unsigned short As[2][BM * BK];
  __shared__ __align__(16) unsigned short Ws[2][BN * BK];
  const int tid = threadIdx.x, lane = tid & 63, wid = tid >> 6;
  const int wr = wid >> 1, wc = wid & 1;
  const int bm = blockIdx.x * BM, bn = blockIdx.y * BN;
  const int srow = lane >> 2;          // row within 16-row group
  const int skoff = (lane & 3) * 8;    // bf16 col offset

  f32x4 acc[AM][BF] = {};

  auto stage = [&](int buf, int kt) {
    #pragma unroll
    for (int i = 0; i < AI; i++) {
      int rowg = (wid * AI + i) * 16;
      gload_lds16(A + (size_t)(bm + rowg + srow) * K + kt + skoff,
                  &As[buf][rowg * BK]);
    }
    #pragma unroll
    for (int i = 0; i < BI; i++) {
      int rowg = (wid * BI + i) * 16;
      gload_lds16(W + (size_t)(bn + rowg + srow) * K + kt + skoff,
                  &Ws[buf][rowg * BK]);
    }
  };

  stage(0, 0);
  __syncthreads();
  const int nt = K / BK;
  int cur = 0;
  for (int t = 0; t < nt; t++) {
    if (t + 1 < nt) stage(cur ^ 1, (t + 1) * BK);
    short8 af[AM], bfr[BF];
    #pragma unroll
    for (int i = 0; i < AM; i++)
      af[i] = *reinterpret_cast<const short8*>(
          &As[cur][(wr * WM + i * 16 + (lane & 15)) * BK + (lane >> 4) * 8]);
    #pragma unroll
    for (int j = 0; j < BF; j++)
      bfr[j] = *reinterpret_cast<const short8*>(
          &Ws[cur][(wc * WN + j * 16 + (lane & 15)) * BK + (lane >> 4) * 8]);
    #pragma unroll
    for (int i = 0; i < AM; i++)
      #pragma unroll
      for (int j = 0; j < BF; j++)
        acc[i][j] = __builtin_amdgcn_mfma_f32_16x16x32_bf16(af[i], bfr[j], acc[i][j], 0, 0, 0);
    __syncthreads();
    cur ^= 1;
  }

  float sv = 0.f;
  if constexpr (EPI == EPI_SKIPX) sv = sscale[0];

  #pragma unroll
  for (int i = 0; i < AM; i++) {
    #pragma unroll
    for (int j = 0; j < BF; j++) {
      int row0 = bm + wr * WM + i * 16 + ((lane >> 4) << 2);
      int col  = bn + wc * WN + j * 16 + (lane & 15);
      #pragma unroll
      for (int r = 0; r < 4; r++) {
        float v = acc[i][j][r];
        size_t off = (size_t)(row0 + r) * N + col;
        if constexpr (EPI == EPI_SKIPX) v += sv * X[off];
        if constexpr (EPI == EPI_BIAS)  v += bias[col];
        if constexpr (sizeof(OT) == 2) C[off] = (OT)f2bf(v);
        else                           C[off] = v;
      }
    }
  }
}

// ---------------- x_proj MFMA GEMM: N=48, pipelined -------------------------
__global__ __launch_bounds__(256) void gemm_mfma48(
    const unsigned short* __restrict__ A, const unsigned short* __restrict__ W,
    float* __restrict__ C, int K)
{
  __shared__ __align__(16) unsigned short As[2][64 * 32];
  __shared__ __align__(16) unsigned short Ws[2][48 * 32];
  const int tid = threadIdx.x, lane = tid & 63, wid = tid >> 6;
  const int bm = blockIdx.x * 64;
  const int srow = lane >> 2, skoff = (lane & 3) * 8;

  f32x4 acc[3] = {};

  auto stage = [&](int buf, int kt) {
    int rowg = wid * 16;
    gload_lds16(A + (size_t)(bm + rowg + srow) * K + kt + skoff, &As[buf][rowg * 32]);
    if (wid < 3)
      gload_lds16(W + (size_t)(rowg + srow) * K + kt + skoff, &Ws[buf][rowg * 32]);
  };

  stage(0, 0);
  __syncthreads();
  const int nt = K / 32;
  int cur = 0;
  for (int t = 0; t < nt; t++) {
    if (t + 1 < nt) stage(cur ^ 1, (t + 1) * 32);
    short8 af = *reinterpret_cast<const short8*>(
        &As[cur][(wid * 16 + (lane & 15)) * 32 + (lane >> 4) * 8]);
    #pragma unroll
    for (int j = 0; j < 3; j++) {
      short8 bfr = *reinterpret_cast<const short8*>(
          &Ws[cur][(j * 16 + (lane & 15)) * 32 + (lane >> 4) * 8]);
      acc[j] = __builtin_amdgcn_mfma_f32_16x16x32_bf16(af, bfr, acc[j], 0, 0, 0);
    }
    __syncthreads();
    cur ^= 1;
  }
  int row0 = bm + wid * 16 + ((lane >> 4) << 2);
  #pragma unroll
  for (int j = 0; j < 3; j++) {
    int col = j * 16 + (lane & 15);
    #pragma unroll
    for (int r = 0; r < 4; r++)
      C[(size_t)(row0 + r) * 48 + col] = acc[j][r];
  }
}

// ------ depthwise causal conv (k=4) + SiLU, bf16 in/out ---------------------
__global__ __launch_bounds__(256) void conv_silu_kernel(
    const unsigned short* __restrict__ xz, const float* __restrict__ cw,
    const float* __restrict__ cb, unsigned short* __restrict__ xc_bf)
{
  int idx = blockIdx.x * 256 + threadIdx.x;   // B*L*128
  int d4 = (idx & 127) << 2;
  int bt = idx >> 7;
  int t  = bt & (LSEQ - 1);
  int b  = bt >> 12;
  float a0 = cb[d4], a1 = cb[d4+1], a2 = cb[d4+2], a3 = cb[d4+3];
  float4 w0 = *reinterpret_cast<const float4*>(&cw[(d4+0)*4]);
  float4 w1 = *reinterpret_cast<const float4*>(&cw[(d4+1)*4]);
  float4 w2 = *reinterpret_cast<const float4*>(&cw[(d4+2)*4]);
  float4 w3 = *reinterpret_cast<const float4*>(&cw[(d4+3)*4]);
  const float* wp0 = (const float*)&w0;
  const float* wp1 = (const float*)&w1;
  const float* wp2 = (const float*)&w2;
  const float* wp3 = (const float*)&w3;
  #pragma unroll
  for (int j = 0; j < 4; j++) {
    int tt = t - 3 + j;
    if (tt >= 0) {
      ushort4 xv = *reinterpret_cast<const ushort4*>(&xz[((size_t)b*LSEQ + tt)*1024 + d4]);
      a0 += wp0[j]*bf2f(xv.x); a1 += wp1[j]*bf2f(xv.y);
      a2 += wp2[j]*bf2f(xv.z); a3 += wp3[j]*bf2f(xv.w);
    }
  }
  ushort4 ob;
  ob.x = f2bf(a0 / (1.f + __expf(-a0)));
  ob.y = f2bf(a1 / (1.f + __expf(-a1)));
  ob.z = f2bf(a2 / (1.f + __expf(-a2)));
  ob.w = f2bf(a3 / (1.f + __expf(-a3)));
  *reinterpret_cast<ushort4*>(&xc_bf[((size_t)b*LSEQ + t)*512 + d4]) = ob;
}

// ------ dt_proj v2: weights cached in registers, 16 rows/block, bf16 out ----
__global__ __launch_bounds__(256) void dtproj2_kernel(
    const float* __restrict__ dbc, const float* __restrict__ dpw,
    const float* __restrict__ dpb, unsigned short* __restrict__ delta_bf)
{
  const int tid = threadIdx.x;
  const int d0 = (tid & 127) << 2;
  float4 w[4][4];
  #pragma unroll
  for (int dd = 0; dd < 4; dd++) {
    const float4* wr = reinterpret_cast<const float4*>(&dpw[(d0+dd)*16]);
    w[dd][0] = wr[0]; w[dd][1] = wr[1]; w[dd][2] = wr[2]; w[dd][3] = wr[3];
  }
  float4 bias = *reinterpret_cast<const float4*>(&dpb[d0]);
  const float* bp = (const float*)&bias;
  size_t rbase = (size_t)blockIdx.x * DROWS + (tid >> 7);
  #pragma unroll 2
  for (int rr = 0; rr < DROWS; rr += 2) {
    size_t r = rbase + rr;
    const float4* dt = reinterpret_cast<const float4*>(dbc + r*48);
    float4 t0 = dt[0], t1 = dt[1], t2 = dt[2], t3 = dt[3];
    ushort4 ob;
    unsigned short* obp = (unsigned short*)&ob;
    #pragma unroll
    for (int dd = 0; dd < 4; dd++) {
      float acc = bp[dd];
      acc += t0.x*w[dd][0].x + t0.y*w[dd][0].y + t0.z*w[dd][0].z + t0.w*w[dd][0].w;
      acc += t1.x*w[dd][1].x + t1.y*w[dd][1].y + t1.z*w[dd][1].z + t1.w*w[dd][1].w;
      acc += t2.x*w[dd][2].x + t2.y*w[dd][2].y + t2.z*w[dd][2].z + t2.w*w[dd][2].w;
      acc += t3.x*w[dd][3].x + t3.y*w[dd][3].y + t3.z*w[dd][3].z + t3.w*w[dd][3].w;
      obp[dd] = f2bf(fmaxf(acc, 0.f) + log1pf(__expf(-fabsf(acc))));
    }
    *reinterpret_cast<ushort4*>(&delta_bf[r*512 + d0]) = ob;
  }
}

// ---------------- selective scan, chunked, n-split x2, CL=8 -----------------
__global__ __launch_bounds__(256) void scanA_kernel(
    const unsigned short* __restrict__ delta_bf, const unsigned short* __restrict__ xc_bf,
    const float* __restrict__ dbc, const float* __restrict__ Ar_tab,
    unsigned short* __restrict__ hloc, float* __restrict__ Ssum)
{
  __shared__ float Bs[CL][16];
  const int tid = threadIdx.x;
  int g = blockIdx.x * 256 + tid;
  int nh = g & 1;
  int d  = (g >> 1) & 511;
  int c  = (g >> 10) & (NCH - 1);
  int b  = g >> 19;
  size_t tbase = (size_t)b * LSEQ + (size_t)c * CL;
  if (tid < CL * 16)
    Bs[tid >> 4][tid & 15] = dbc[(tbase + (tid >> 4)) * 48 + 16 + (tid & 15)];
  const float4* Ap = reinterpret_cast<const float4*>(Ar_tab + d*16 + nh*8);
  float4 A0 = Ap[0], A1 = Ap[1];
  float Ar[8] = {A0.x, A0.y, A0.z, A0.w, A1.x, A1.y, A1.z, A1.w};
  float h[8] = {};
  float S = 0.f;
  __syncthreads();
  #pragma unroll
  for (int t = 0; t < CL; t++) {
    size_t r = tbase + t;
    float dl = bf2f(delta_bf[r*512 + d]);
    float u  = bf2f(xc_bf[r*512 + d]);
    float du = dl * u;
    S += dl;
    float4 B0 = *reinterpret_cast<const float4*>(&Bs[t][nh*8]);
    float4 B1 = *reinterpret_cast<const float4*>(&Bs[t][nh*8 + 4]);
    float Bv[8] = {B0.x,B0.y,B0.z,B0.w, B1.x,B1.y,B1.z,B1.w};
    #pragma unroll
    for (int n = 0; n < 8; n++)
      h[n] = __expf(dl * Ar[n]) * h[n] + du * Bv[n];
  }
  size_t o = (((size_t)c * B_SZ + b) * 512 + d) * 16 + nh*8;
  short8 hs;
  #pragma unroll
  for (int n = 0; n < 8; n++) hs[n] = (short)f2bf(h[n]);
  *reinterpret_cast<short8*>(&hloc[o]) = hs;
  if (nh == 0) Ssum[((size_t)c * B_SZ + b) * 512 + d] = S;
}

// ---- hierarchical chunk-combine: NG groups of GC chunks per (b,d,n) --------
// pass 1: per-(b,grp,d,n) group aggregate (E = prod e_c, V = fold)
__global__ __launch_bounds__(256) void scanmidA_kernel(
    const unsigned short* __restrict__ hloc, const float* __restrict__ Ssum,
    const float* __restrict__ Ar_tab, float* __restrict__ Eg, float* __restrict__ Vg)
{
  int blk = blockIdx.x;                 // b*NG*32 + grp*32 + dblk
  int dblk = blk & 31;
  int grp  = (blk >> 5) & (NG - 1);
  int b    = blk >> 9;
  int n  = threadIdx.x & 15, dlo = threadIdx.x >> 4;
  int d  = dblk * 16 + dlo;
  float Ar = Ar_tab[d*16 + n];
  float E = 1.f, V = 0.f;
  #pragma unroll 4
  for (int i = 0; i < GC; i++) {
    int c = grp * GC + i;
    size_t idx = ((size_t)c * B_SZ + b) * 512 + d;
    float Ec = __expf(Ssum[idx] * Ar);
    V = Ec * V + bf2f(hloc[idx*16 + n]);
    E *= Ec;
  }
  size_t o = (size_t)grp * (B_SZ*8192) + (size_t)b * 8192 + d*16 + n;
  Eg[o] = E;
  Vg[o] = V;
}

// pass 2: serial fold over NG groups per (b,d,n) -> group-entry states
__global__ __launch_bounds__(256) void scanmidB_kernel(
    const float* __restrict__ Eg, const float* __restrict__ Vg,
    float* __restrict__ Gent)
{
  int g = blockIdx.x * 256 + threadIdx.x;   // B*8192 = 16384
  float h = 0.f;
  #pragma unroll
  for (int grp = 0; grp < NG; grp++) {
    size_t o = (size_t)grp * (B_SZ*8192) + g;
    Gent[o] = h;
    h = Eg[o] * h + Vg[o];
  }
}

// pass 3: re-walk own group, writing per-chunk entry states (bf16)
__global__ __launch_bounds__(256) void scanmidC_kernel(
    const unsigned short* __restrict__ hloc, const float* __restrict__ Ssum,
    const float* __restrict__ Ar_tab, const float* __restrict__ Gent,
    unsigned short* __restrict__ henter)
{
  int blk = blockIdx.x;
  int dblk = blk & 31;
  int grp  = (blk >> 5) & (NG - 1);
  int b    = blk >> 9;
  int n  = threadIdx.x & 15, dlo = threadIdx.x >> 4;
  int d  = dblk * 16 + dlo;
  float Ar = Ar_tab[d*16 + n];
  float h = Gent[(size_t)grp * (B_SZ*8192) + (size_t)b * 8192 + d*16 + n];
  #pragma unroll 4
  for (int i = 0; i < GC; i++) {
    int c = grp * GC + i;
    size_t idx = ((size_t)c * B_SZ + b) * 512 + d;
    henter[idx*16 + n] = f2bf(h);
    h = __expf(Ssum[idx] * Ar) * h + bf2f(hloc[idx*16 + n]);
  }
}

__global__ __launch_bounds__(256) void scanB_kernel(
    const unsigned short* __restrict__ delta_bf, const unsigned short* __restrict__ xc_bf,
    const float* __restrict__ dbc, const float* __restrict__ Ar_tab,
    const unsigned short* __restrict__ henter, const float* __restrict__ Dskip,
    const unsigned short* __restrict__ xz, unsigned short* __restrict__ y_bf)
{
  __shared__ float Bs[CL][16];
  __shared__ float Cs[CL][16];
  const int tid = threadIdx.x;
  int g = blockIdx.x * 256 + tid;
  int nh = g & 1;
  int d  = (g >> 1) & 511;
  int c  = (g >> 10) & (NCH - 1);
  int b  = g >> 19;
  size_t tbase = (size_t)b * LSEQ + (size_t)c * CL;
  if (tid < CL * 16) {
    int ts = tid >> 4, is = tid & 15;
    Bs[ts][is] = dbc[(tbase + ts) * 48 + 16 + is];
  } else if (tid < 2 * CL * 16) {
    int t2 = tid - CL * 16;
    int ts = t2 >> 4, is = t2 & 15;
    Cs[ts][is] = dbc[(tbase + ts) * 48 + 32 + is];
  }
  const float4* Ap = reinterpret_cast<const float4*>(Ar_tab + d*16 + nh*8);
  float4 A0 = Ap[0], A1 = Ap[1];
  float Ar[8] = {A0.x, A0.y, A0.z, A0.w, A1.x, A1.y, A1.z, A1.w};
  size_t o = (((size_t)c * B_SZ + b) * 512 + d) * 16 + nh*8;
  short8 hv = *reinterpret_cast<const short8*>(&henter[o]);
  float h[8];
  #pragma unroll
  for (int n = 0; n < 8; n++) h[n] = bf2f((unsigned short)hv[n]);
  float Dsk = Dskip[d];
  __syncthreads();
  #pragma unroll
  for (int t = 0; t < CL; t++) {
    size_t r = tbase + t;
    float dl = bf2f(delta_bf[r*512 + d]);
    float u  = bf2f(xc_bf[r*512 + d]);
    float du = dl * u;
    float4 B0 = *reinterpret_cast<const float4*>(&Bs[t][nh*8]);
    float4 B1 = *reinterpret_cast<const float4*>(&Bs[t][nh*8 + 4]);
    float4 C0 = *reinterpret_cast<const float4*>(&Cs[t][nh*8]);
    float4 C1 = *reinterpret_cast<const float4*>(&Cs[t][nh*8 + 4]);
    float Bv[8] = {B0.x,B0.y,B0.z,B0.w, B1.x,B1.y,B1.z,B1.w};
    float Cv[8] = {C0.x,C0.y,C0.z,C0.w, C1.x,C1.y,C1.z,C1.w};
    float yp = 0.f;
    #pragma unroll
    for (int n = 0; n < 8; n++) {
      h[n] = __expf(dl * Ar[n]) * h[n] + du * Bv[n];
      yp += h[n] * Cv[n];
    }
    float y = yp + __shfl_xor(yp, 1);
    if (nh == 0) {
      y += u * Dsk;
      float z = bf2f(xz[r*1024 + 512 + d]);
      float sig = 1.f / (1.f + __expf(-z));
      y_bf[r*512 + d] = f2bf(y * z * sig);
    }
  }
}

// ---------------- launch ----------------------------------------------------
extern "C" void kernel_launch(void* const* d_in, const int* in_sizes, int n_in,
                              void* d_out, int out_size, void* d_ws, size_t ws_size,
                              hipStream_t stream)
{
  const float* x      = (const float*)d_in[0];
  const float* ln_w   = (const float*)d_in[1];
  const float* ln_b   = (const float*)d_in[2];
  const float* inW    = (const float*)d_in[3];
  const float* convW  = (const float*)d_in[4];
  const float* convB  = (const float*)d_in[5];
  const float* xprojW = (const float*)d_in[6];
  const float* dtW    = (const float*)d_in[7];
  const float* dtB    = (const float*)d_in[8];
  const float* A_log  = (const float*)d_in[9];
  const float* Dskip  = (const float*)d_in[10];
  const float* outW   = (const float*)d_in[11];
  const float* projW  = (const float*)d_in[12];
  const float* projB  = (const float*)d_in[13];
  const float* skip   = (const float*)d_in[14];
  float* out = (float*)d_out;

  const size_t BL = (size_t)B_SZ * LSEQ;   // 8192
  char* p = (char*)d_ws;
  unsigned short* xn_bf = (unsigned short*)p;  p += BL*256*2;
  unsigned short* xz_bf = (unsigned short*)p;  p += BL*1024*2;
  unsigned short* xc_bf = (unsigned short*)p;  p += BL*512*2;
  float* dbc    = (float*)p;                   p += BL*48*4;
  unsigned short* delta_bf = (unsigned short*)p; p += BL*512*2;
  unsigned short* hloc   = (unsigned short*)p; p += (size_t)NCH*B_SZ*512*16*2;
  unsigned short* henter = (unsigned short*)p; p += (size_t)NCH*B_SZ*512*16*2;
  float* Ssum   = (float*)p;                   p += (size_t)NCH*B_SZ*512*4;
  unsigned short* y_bf = (unsigned short*)p;   p += BL*512*2;
  unsigned short* inW_bf  = (unsigned short*)p; p += 1024*256*2;
  unsigned short* outW_bf = (unsigned short*)p; p += 256*512*2;
  unsigned short* projW_bf= (unsigned short*)p; p += 256*256*2;
  unsigned short* xprojW_bf=(unsigned short*)p; p += 48*512*2;
  float* Ar_tab = (float*)p;                   p += 512*16*4;
  float* Eg     = (float*)p;                   p += (size_t)NG*B_SZ*8192*4;
  float* Vg     = (float*)p;                   p += (size_t)NG*B_SZ*8192*4;
  float* Gent   = (float*)p;                   p += (size_t)NG*B_SZ*8192*4;
  // overlays (disjoint lifetimes):
  unsigned short* xm_bf  = hloc;    // born after scanB (hloc dead after scanmidC)
  unsigned short* xn2_bf = xn_bf;   // xn_bf dead after in_proj

  prep_kernel<<<2048 + 480, 256, 0, stream>>>(
      x, ln_w, ln_b, xn_bf, inW, inW_bf, outW, outW_bf,
      projW, projW_bf, xprojW, xprojW_bf, A_log, Ar_tab);

  gemm_mfma<128,128,EPI_NONE><<<dim3(BL/128, 1024/128), 256, 0, stream>>>(
      xn_bf, inW_bf, xz_bf, (int)BL, 1024, 256, nullptr, nullptr, nullptr);

  conv_silu_kernel<<<(B_SZ*LSEQ*128)/256, 256, 0, stream>>>(xz_bf, convW, convB, xc_bf);

  gemm_mfma48<<<BL/64, 256, 0, stream>>>(xc_bf, xprojW_bf, dbc, 512);

  dtproj2_kernel<<<BL/DROWS, 256, 0, stream>>>(dbc, dtW, dtB, delta_bf);

  scanA_kernel<<<(B_SZ*NCH*512*2)/256, 256, 0, stream>>>(
      delta_bf, xc_bf, dbc, Ar_tab, hloc, Ssum);
  scanmidA_kernel<<<B_SZ*NG*32, 256, 0, stream>>>(hloc, Ssum, Ar_tab, Eg, Vg);
  scanmidB_kernel<<<B_SZ*8192/256, 256, 0, stream>>>(Eg, Vg, Gent);
  scanmidC_kernel<<<B_SZ*NG*32, 256, 0, stream>>>(hloc, Ssum, Ar_tab, Gent, henter);
  scanB_kernel<<<(B_SZ*NCH*512*2)/256, 256, 0, stream>>>(
      delta_bf, xc_bf, dbc, Ar_tab, henter, Dskip, xz_bf, y_bf);

  gemm_mfma<64,64,EPI_SKIPX><<<dim3(BL/64, 256/64), 256, 0, stream>>>(
      y_bf, outW_bf, xm_bf, (int)BL, 256, 512, x, skip, nullptr);

  ln_bf16_kernel<<<BL/4, 256, 0, stream>>>(xm_bf, ln_w, ln_b, xn2_bf);

  gemm_mfma<64,64,EPI_BIAS><<<dim3(BL/64, 256/64), 256, 0, stream>>>(
      xn2_bf, projW_bf, out, (int)BL, 256, 256, nullptr, nullptr, projB);
}

// Round 16
// 216.672 us; speedup vs baseline: 1.1810x; 1.0009x over previous
//
#include <hip/hip_runtime.h>
#include <hip/hip_bf16.h>

#define B_SZ   2
#define LSEQ   4096
#define NCH    512
#define CL     8
#define NG     16
#define GC     (NCH/NG)   // 32
#define DROWS  16

typedef __attribute__((ext_vector_type(8))) short short8;
typedef __attribute__((ext_vector_type(4))) float f32x4;

__device__ __forceinline__ unsigned short f2bf(float f) {
  union { float f; unsigned u; } x; x.f = f;
  unsigned r = x.u + 0x7fffu + ((x.u >> 16) & 1u);
  return (unsigned short)(r >> 16);
}
__device__ __forceinline__ float bf2f(unsigned short u) {
  union { unsigned u; float f; } x; x.u = (unsigned)u << 16;
  return x.f;
}

// global->LDS direct async copy, 16B per lane; l must be wave-uniform base.
__device__ __forceinline__ void gload_lds16(const unsigned short* g, unsigned short* l) {
  __builtin_amdgcn_global_load_lds(
      (const __attribute__((address_space(1))) unsigned int*)g,
      (__attribute__((address_space(3))) unsigned int*)l, 16, 0, 0);
}

// ---- prep: LN1 (blocks 0..2047) + weight converts + Ar table (blocks 2048+) ----
__global__ __launch_bounds__(256) void prep_kernel(
    const float* __restrict__ x, const float* __restrict__ ln_w,
    const float* __restrict__ ln_b, unsigned short* __restrict__ xn_bf,
    const float* __restrict__ inW,  unsigned short* __restrict__ inW_bf,
    const float* __restrict__ outW, unsigned short* __restrict__ outW_bf,
    const float* __restrict__ projW, unsigned short* __restrict__ projW_bf,
    const float* __restrict__ xprojW, unsigned short* __restrict__ xprojW_bf,
    const float* __restrict__ A_log, float* __restrict__ Ar_tab)
{
  if (blockIdx.x < 2048) {
    int wv = threadIdx.x >> 6, lane = threadIdx.x & 63;
    size_t row = (size_t)blockIdx.x * 4 + wv;
    float4 v = reinterpret_cast<const float4*>(x)[row * 64 + lane];
    float s  = v.x + v.y + v.z + v.w;
    float sq = v.x*v.x + v.y*v.y + v.z*v.z + v.w*v.w;
    #pragma unroll
    for (int off = 32; off; off >>= 1) {
      s  += __shfl_xor(s,  off);
      sq += __shfl_xor(sq, off);
    }
    float mu  = s * (1.f/256.f);
    float var = sq * (1.f/256.f) - mu*mu;
    float rs  = rsqrtf(var + 1e-5f);
    float4 wv4 = reinterpret_cast<const float4*>(ln_w)[lane];
    float4 bv4 = reinterpret_cast<const float4*>(ln_b)[lane];
    ushort4 o;
    o.x = f2bf((v.x-mu)*rs*wv4.x + bv4.x);
    o.y = f2bf((v.y-mu)*rs*wv4.y + bv4.y);
    o.z = f2bf((v.z-mu)*rs*wv4.z + bv4.z);
    o.w = f2bf((v.w-mu)*rs*wv4.w + bv4.w);
    reinterpret_cast<ushort4*>(xn_bf)[row * 64 + lane] = o;
    return;
  }
  int j = (blockIdx.x - 2048) * 256 + threadIdx.x;
  const float* src; unsigned short* dst; int off;
  if (j < 65536)       { src = inW;    dst = inW_bf;    off = j; }
  else if (j < 98304)  { src = outW;   dst = outW_bf;   off = j - 65536; }
  else if (j < 114688) { src = projW;  dst = projW_bf;  off = j - 98304; }
  else if (j < 120832) { src = xprojW; dst = xprojW_bf; off = j - 114688; }
  else {
    int a = (j - 120832) * 4;
    float4 v = *reinterpret_cast<const float4*>(A_log + a);
    float4 o = {-__expf(v.x), -__expf(v.y), -__expf(v.z), -__expf(v.w)};
    *reinterpret_cast<float4*>(Ar_tab + a) = o;
    return;
  }
  float4 v = *reinterpret_cast<const float4*>(src + off*4);
  ushort4 o;
  o.x = f2bf(v.x); o.y = f2bf(v.y); o.z = f2bf(v.z); o.w = f2bf(v.w);
  *reinterpret_cast<ushort4*>(dst + off*4) = o;
}

// ---------------- LN2: bf16 in, bf16 out ------------------------------------
__global__ __launch_bounds__(256) void ln_bf16_kernel(
    const unsigned short* __restrict__ in, const float* __restrict__ w,
    const float* __restrict__ b, unsigned short* __restrict__ out)
{
  int wv = threadIdx.x >> 6, lane = threadIdx.x & 63;
  size_t row = (size_t)blockIdx.x * 4 + wv;
  ushort4 uv = reinterpret_cast<const ushort4*>(in)[row * 64 + lane];
  float4 v = {bf2f(uv.x), bf2f(uv.y), bf2f(uv.z), bf2f(uv.w)};
  float s  = v.x + v.y + v.z + v.w;
  float sq = v.x*v.x + v.y*v.y + v.z*v.z + v.w*v.w;
  #pragma unroll
  for (int off = 32; off; off >>= 1) {
    s  += __shfl_xor(s,  off);
    sq += __shfl_xor(sq, off);
  }
  float mu  = s * (1.f/256.f);
  float var = sq * (1.f/256.f) - mu*mu;
  float rs  = rsqrtf(var + 1e-5f);
  float4 wv4 = reinterpret_cast<const float4*>(w)[lane];
  float4 bv4 = reinterpret_cast<const float4*>(b)[lane];
  ushort4 o;
  o.x = f2bf((v.x-mu)*rs*wv4.x + bv4.x);
  o.y = f2bf((v.y-mu)*rs*wv4.y + bv4.y);
  o.z = f2bf((v.z-mu)*rs*wv4.z + bv4.z);
  o.w = f2bf((v.w-mu)*rs*wv4.w + bv4.w);
  reinterpret_cast<ushort4*>(out)[row * 64 + lane] = o;
}

// ------ bf16 MFMA GEMM, global_load_lds + dbuf pipeline: C = A * W^T --------
enum { EPI_NONE = 0, EPI_SKIPX = 1, EPI_BIAS = 2 };

template<int BM, int BN, int EPI, typename OT>
__global__ __launch_bounds__(256) void gemm_mfma(
    const unsigned short* __restrict__ A, const unsigned short* __restrict__ W,
    OT* __restrict__ C, int M, int N, int K,
    const float* __restrict__ X, const float* __restrict__ sscale,
    const float* __restrict__ bias)
{
  constexpr int BK = 32;
  constexpr int WM = BM / 2, WN = BN / 2;       // 2x2 waves
  constexpr int AM = WM / 16, BF = WN / 16;
  constexpr int AI = BM / 64, BI = BN / 64;     // stage instrs per wave
  __shared__ __align__(16) unsigned short As[2][BM * BK];
  __shared__ __align__(16) unsigned short Ws[2][BN * BK];
  const int tid = threadIdx.x, lane = tid & 63, wid = tid >> 6;
  const int wr = wid >> 1, wc = wid & 1;
  const int bm = blockIdx.x * BM, bn = blockIdx.y * BN;
  const int srow = lane >> 2;          // row within 16-row group
  const int skoff = (lane & 3) * 8;    // bf16 col offset

  f32x4 acc[AM][BF] = {};

  auto stage = [&](int buf, int kt) {
    #pragma unroll
    for (int i = 0; i < AI; i++) {
      int rowg = (wid * AI + i) * 16;
      gload_lds16(A + (size_t)(bm + rowg + srow) * K + kt + skoff,
                  &As[buf][rowg * BK]);
    }
    #pragma unroll
    for (int i = 0; i < BI; i++) {
      int rowg = (wid * BI + i) * 16;
      gload_lds16(W + (size_t)(bn + rowg + srow) * K + kt + skoff,
                  &Ws[buf][rowg * BK]);
    }
  };

  stage(0, 0);
  __syncthreads();
  const int nt = K / BK;
  int cur = 0;
  for (int t = 0; t < nt; t++) {
    if (t + 1 < nt) stage(cur ^ 1, (t + 1) * BK);
    short8 af[AM], bfr[BF];
    #pragma unroll
    for (int i = 0; i < AM; i++)
      af[i] = *reinterpret_cast<const short8*>(
          &As[cur][(wr * WM + i * 16 + (lane & 15)) * BK + (lane >> 4) * 8]);
    #pragma unroll
    for (int j = 0; j < BF; j++)
      bfr[j] = *reinterpret_cast<const short8*>(
          &Ws[cur][(wc * WN + j * 16 + (lane & 15)) * BK + (lane >> 4) * 8]);
    #pragma unroll
    for (int i = 0; i < AM; i++)
      #pragma unroll
      for (int j = 0; j < BF; j++)
        acc[i][j] = __builtin_amdgcn_mfma_f32_16x16x32_bf16(af[i], bfr[j], acc[i][j], 0, 0, 0);
    __syncthreads();
    cur ^= 1;
  }

  float sv = 0.f;
  if constexpr (EPI == EPI_SKIPX) sv = sscale[0];

  #pragma unroll
  for (int i = 0; i < AM; i++) {
    #pragma unroll
    for (int j = 0; j < BF; j++) {
      int row0 = bm + wr * WM + i * 16 + ((lane >> 4) << 2);
      int col  = bn + wc * WN + j * 16 + (lane & 15);
      #pragma unroll
      for (int r = 0; r < 4; r++) {
        float v = acc[i][j][r];
        size_t off = (size_t)(row0 + r) * N + col;
        if constexpr (EPI == EPI_SKIPX) v += sv * X[off];
        if constexpr (EPI == EPI_BIAS)  v += bias[col];
        if constexpr (sizeof(OT) == 2) C[off] = (OT)f2bf(v);
        else                           C[off] = v;
      }
    }
  }
}

// ---------------- x_proj MFMA GEMM: N=48, pipelined -------------------------
__global__ __launch_bounds__(256) void gemm_mfma48(
    const unsigned short* __restrict__ A, const unsigned short* __restrict__ W,
    float* __restrict__ C, int K)
{
  __shared__ __align__(16) unsigned short As[2][64 * 32];
  __shared__ __align__(16) unsigned short Ws[2][48 * 32];
  const int tid = threadIdx.x, lane = tid & 63, wid = tid >> 6;
  const int bm = blockIdx.x * 64;
  const int srow = lane >> 2, skoff = (lane & 3) * 8;

  f32x4 acc[3] = {};

  auto stage = [&](int buf, int kt) {
    int rowg = wid * 16;
    gload_lds16(A + (size_t)(bm + rowg + srow) * K + kt + skoff, &As[buf][rowg * 32]);
    if (wid < 3)
      gload_lds16(W + (size_t)(rowg + srow) * K + kt + skoff, &Ws[buf][rowg * 32]);
  };

  stage(0, 0);
  __syncthreads();
  const int nt = K / 32;
  int cur = 0;
  for (int t = 0; t < nt; t++) {
    if (t + 1 < nt) stage(cur ^ 1, (t + 1) * 32);
    short8 af = *reinterpret_cast<const short8*>(
        &As[cur][(wid * 16 + (lane & 15)) * 32 + (lane >> 4) * 8]);
    #pragma unroll
    for (int j = 0; j < 3; j++) {
      short8 bfr = *reinterpret_cast<const short8*>(
          &Ws[cur][(j * 16 + (lane & 15)) * 32 + (lane >> 4) * 8]);
      acc[j] = __builtin_amdgcn_mfma_f32_16x16x32_bf16(af, bfr, acc[j], 0, 0, 0);
    }
    __syncthreads();
    cur ^= 1;
  }
  int row0 = bm + wid * 16 + ((lane >> 4) << 2);
  #pragma unroll
  for (int j = 0; j < 3; j++) {
    int col = j * 16 + (lane & 15);
    #pragma unroll
    for (int r = 0; r < 4; r++)
      C[(size_t)(row0 + r) * 48 + col] = acc[j][r];
  }
}

// ------ depthwise causal conv (k=4) + SiLU, bf16 in/out ---------------------
__global__ __launch_bounds__(256) void conv_silu_kernel(
    const unsigned short* __restrict__ xz, const float* __restrict__ cw,
    const float* __restrict__ cb, unsigned short* __restrict__ xc_bf)
{
  int idx = blockIdx.x * 256 + threadIdx.x;   // B*L*128
  int d4 = (idx & 127) << 2;
  int bt = idx >> 7;
  int t  = bt & (LSEQ - 1);
  int b  = bt >> 12;
  float a0 = cb[d4], a1 = cb[d4+1], a2 = cb[d4+2], a3 = cb[d4+3];
  float4 w0 = *reinterpret_cast<const float4*>(&cw[(d4+0)*4]);
  float4 w1 = *reinterpret_cast<const float4*>(&cw[(d4+1)*4]);
  float4 w2 = *reinterpret_cast<const float4*>(&cw[(d4+2)*4]);
  float4 w3 = *reinterpret_cast<const float4*>(&cw[(d4+3)*4]);
  const float* wp0 = (const float*)&w0;
  const float* wp1 = (const float*)&w1;
  const float* wp2 = (const float*)&w2;
  const float* wp3 = (const float*)&w3;
  #pragma unroll
  for (int j = 0; j < 4; j++) {
    int tt = t - 3 + j;
    if (tt >= 0) {
      ushort4 xv = *reinterpret_cast<const ushort4*>(&xz[((size_t)b*LSEQ + tt)*1024 + d4]);
      a0 += wp0[j]*bf2f(xv.x); a1 += wp1[j]*bf2f(xv.y);
      a2 += wp2[j]*bf2f(xv.z); a3 += wp3[j]*bf2f(xv.w);
    }
  }
  ushort4 ob;
  ob.x = f2bf(a0 / (1.f + __expf(-a0)));
  ob.y = f2bf(a1 / (1.f + __expf(-a1)));
  ob.z = f2bf(a2 / (1.f + __expf(-a2)));
  ob.w = f2bf(a3 / (1.f + __expf(-a3)));
  *reinterpret_cast<ushort4*>(&xc_bf[((size_t)b*LSEQ + t)*512 + d4]) = ob;
}

// ------ dt_proj v2: weights cached in registers, 16 rows/block, bf16 out ----
__global__ __launch_bounds__(256) void dtproj2_kernel(
    const float* __restrict__ dbc, const float* __restrict__ dpw,
    const float* __restrict__ dpb, unsigned short* __restrict__ delta_bf)
{
  const int tid = threadIdx.x;
  const int d0 = (tid & 127) << 2;
  float4 w[4][4];
  #pragma unroll
  for (int dd = 0; dd < 4; dd++) {
    const float4* wr = reinterpret_cast<const float4*>(&dpw[(d0+dd)*16]);
    w[dd][0] = wr[0]; w[dd][1] = wr[1]; w[dd][2] = wr[2]; w[dd][3] = wr[3];
  }
  float4 bias = *reinterpret_cast<const float4*>(&dpb[d0]);
  const float* bp = (const float*)&bias;
  size_t rbase = (size_t)blockIdx.x * DROWS + (tid >> 7);
  #pragma unroll 2
  for (int rr = 0; rr < DROWS; rr += 2) {
    size_t r = rbase + rr;
    const float4* dt = reinterpret_cast<const float4*>(dbc + r*48);
    float4 t0 = dt[0], t1 = dt[1], t2 = dt[2], t3 = dt[3];
    ushort4 ob;
    unsigned short* obp = (unsigned short*)&ob;
    #pragma unroll
    for (int dd = 0; dd < 4; dd++) {
      float acc = bp[dd];
      acc += t0.x*w[dd][0].x + t0.y*w[dd][0].y + t0.z*w[dd][0].z + t0.w*w[dd][0].w;
      acc += t1.x*w[dd][1].x + t1.y*w[dd][1].y + t1.z*w[dd][1].z + t1.w*w[dd][1].w;
      acc += t2.x*w[dd][2].x + t2.y*w[dd][2].y + t2.z*w[dd][2].z + t2.w*w[dd][2].w;
      acc += t3.x*w[dd][3].x + t3.y*w[dd][3].y + t3.z*w[dd][3].z + t3.w*w[dd][3].w;
      obp[dd] = f2bf(fmaxf(acc, 0.f) + log1pf(__expf(-fabsf(acc))));
    }
    *reinterpret_cast<ushort4*>(&delta_bf[r*512 + d0]) = ob;
  }
}

// ---------------- selective scan, chunked, n-split x2, CL=8 -----------------
__global__ __launch_bounds__(256) void scanA_kernel(
    const unsigned short* __restrict__ delta_bf, const unsigned short* __restrict__ xc_bf,
    const float* __restrict__ dbc, const float* __restrict__ Ar_tab,
    unsigned short* __restrict__ hloc, float* __restrict__ Ssum)
{
  __shared__ float Bs[CL][16];
  const int tid = threadIdx.x;
  int g = blockIdx.x * 256 + tid;
  int nh = g & 1;
  int d  = (g >> 1) & 511;
  int c  = (g >> 10) & (NCH - 1);
  int b  = g >> 19;
  size_t tbase = (size_t)b * LSEQ + (size_t)c * CL;
  if (tid < CL * 16)
    Bs[tid >> 4][tid & 15] = dbc[(tbase + (tid >> 4)) * 48 + 16 + (tid & 15)];
  const float4* Ap = reinterpret_cast<const float4*>(Ar_tab + d*16 + nh*8);
  float4 A0 = Ap[0], A1 = Ap[1];
  float Ar[8] = {A0.x, A0.y, A0.z, A0.w, A1.x, A1.y, A1.z, A1.w};
  float h[8] = {};
  float S = 0.f;
  __syncthreads();
  #pragma unroll
  for (int t = 0; t < CL; t++) {
    size_t r = tbase + t;
    float dl = bf2f(delta_bf[r*512 + d]);
    float u  = bf2f(xc_bf[r*512 + d]);
    float du = dl * u;
    S += dl;
    float4 B0 = *reinterpret_cast<const float4*>(&Bs[t][nh*8]);
    float4 B1 = *reinterpret_cast<const float4*>(&Bs[t][nh*8 + 4]);
    float Bv[8] = {B0.x,B0.y,B0.z,B0.w, B1.x,B1.y,B1.z,B1.w};
    #pragma unroll
    for (int n = 0; n < 8; n++)
      h[n] = __expf(dl * Ar[n]) * h[n] + du * Bv[n];
  }
  size_t o = (((size_t)c * B_SZ + b) * 512 + d) * 16 + nh*8;
  short8 hs;
  #pragma unroll
  for (int n = 0; n < 8; n++) hs[n] = (short)f2bf(h[n]);
  *reinterpret_cast<short8*>(&hloc[o]) = hs;
  if (nh == 0) Ssum[((size_t)c * B_SZ + b) * 512 + d] = S;
}

// ---- hierarchical chunk-combine: NG groups of GC chunks per (b,d,n) --------
// pass 1: per-(b,grp,d,n) group aggregate (E = prod e_c, V = fold)
__global__ __launch_bounds__(256) void scanmidA_kernel(
    const unsigned short* __restrict__ hloc, const float* __restrict__ Ssum,
    const float* __restrict__ Ar_tab, float* __restrict__ Eg, float* __restrict__ Vg)
{
  int blk = blockIdx.x;                 // b*NG*32 + grp*32 + dblk
  int dblk = blk & 31;
  int grp  = (blk >> 5) & (NG - 1);
  int b    = blk >> 9;
  int n  = threadIdx.x & 15, dlo = threadIdx.x >> 4;
  int d  = dblk * 16 + dlo;
  float Ar = Ar_tab[d*16 + n];
  float E = 1.f, V = 0.f;
  #pragma unroll 4
  for (int i = 0; i < GC; i++) {
    int c = grp * GC + i;
    size_t idx = ((size_t)c * B_SZ + b) * 512 + d;
    float Ec = __expf(Ssum[idx] * Ar);
    V = Ec * V + bf2f(hloc[idx*16 + n]);
    E *= Ec;
  }
  size_t o = (size_t)grp * (B_SZ*8192) + (size_t)b * 8192 + d*16 + n;
  Eg[o] = E;
  Vg[o] = V;
}

// pass 2 (fused lookback) + pass 3: fold earlier groups' aggregates, then
// re-walk own group writing per-chunk entry states (bf16)
__global__ __launch_bounds__(256) void scanmidC_kernel(
    const unsigned short* __restrict__ hloc, const float* __restrict__ Ssum,
    const float* __restrict__ Ar_tab, const float* __restrict__ Eg,
    const float* __restrict__ Vg, unsigned short* __restrict__ henter)
{
  int blk = blockIdx.x;
  int dblk = blk & 31;
  int grp  = (blk >> 5) & (NG - 1);
  int b    = blk >> 9;
  int n  = threadIdx.x & 15, dlo = threadIdx.x >> 4;
  int d  = dblk * 16 + dlo;
  float Ar = Ar_tab[d*16 + n];
  size_t e = (size_t)b * 8192 + d*16 + n;
  float h = 0.f;
  for (int g2 = 0; g2 < grp; g2++) {
    size_t o2 = (size_t)g2 * (B_SZ*8192) + e;
    h = Eg[o2] * h + Vg[o2];
  }
  #pragma unroll 4
  for (int i = 0; i < GC; i++) {
    int c = grp * GC + i;
    size_t idx = ((size_t)c * B_SZ + b) * 512 + d;
    henter[idx*16 + n] = f2bf(h);
    h = __expf(Ssum[idx] * Ar) * h + bf2f(hloc[idx*16 + n]);
  }
}

__global__ __launch_bounds__(256) void scanB_kernel(
    const unsigned short* __restrict__ delta_bf, const unsigned short* __restrict__ xc_bf,
    const float* __restrict__ dbc, const float* __restrict__ Ar_tab,
    const unsigned short* __restrict__ henter, const float* __restrict__ Dskip,
    const unsigned short* __restrict__ xz, unsigned short* __restrict__ y_bf)
{
  __shared__ float Bs[CL][16];
  __shared__ float Cs[CL][16];
  const int tid = threadIdx.x;
  int g = blockIdx.x * 256 + tid;
  int nh = g & 1;
  int d  = (g >> 1) & 511;
  int c  = (g >> 10) & (NCH - 1);
  int b  = g >> 19;
  size_t tbase = (size_t)b * LSEQ + (size_t)c * CL;
  if (tid < CL * 16) {
    int ts = tid >> 4, is = tid & 15;
    Bs[ts][is] = dbc[(tbase + ts) * 48 + 16 + is];
  } else if (tid < 2 * CL * 16) {
    int t2 = tid - CL * 16;
    int ts = t2 >> 4, is = t2 & 15;
    Cs[ts][is] = dbc[(tbase + ts) * 48 + 32 + is];
  }
  const float4* Ap = reinterpret_cast<const float4*>(Ar_tab + d*16 + nh*8);
  float4 A0 = Ap[0], A1 = Ap[1];
  float Ar[8] = {A0.x, A0.y, A0.z, A0.w, A1.x, A1.y, A1.z, A1.w};
  size_t o = (((size_t)c * B_SZ + b) * 512 + d) * 16 + nh*8;
  short8 hv = *reinterpret_cast<const short8*>(&henter[o]);
  float h[8];
  #pragma unroll
  for (int n = 0; n < 8; n++) h[n] = bf2f((unsigned short)hv[n]);
  float Dsk = Dskip[d];
  __syncthreads();
  #pragma unroll
  for (int t = 0; t < CL; t++) {
    size_t r = tbase + t;
    float dl = bf2f(delta_bf[r*512 + d]);
    float u  = bf2f(xc_bf[r*512 + d]);
    float du = dl * u;
    float4 B0 = *reinterpret_cast<const float4*>(&Bs[t][nh*8]);
    float4 B1 = *reinterpret_cast<const float4*>(&Bs[t][nh*8 + 4]);
    float4 C0 = *reinterpret_cast<const float4*>(&Cs[t][nh*8]);
    float4 C1 = *reinterpret_cast<const float4*>(&Cs[t][nh*8 + 4]);
    float Bv[8] = {B0.x,B0.y,B0.z,B0.w, B1.x,B1.y,B1.z,B1.w};
    float Cv[8] = {C0.x,C0.y,C0.z,C0.w, C1.x,C1.y,C1.z,C1.w};
    float yp = 0.f;
    #pragma unroll
    for (int n = 0; n < 8; n++) {
      h[n] = __expf(dl * Ar[n]) * h[n] + du * Bv[n];
      yp += h[n] * Cv[n];
    }
    float y = yp + __shfl_xor(yp, 1);
    if (nh == 0) {
      y += u * Dsk;
      float z = bf2f(xz[r*1024 + 512 + d]);
      float sig = 1.f / (1.f + __expf(-z));
      y_bf[r*512 + d] = f2bf(y * z * sig);
    }
  }
}

// ---------------- launch ----------------------------------------------------
extern "C" void kernel_launch(void* const* d_in, const int* in_sizes, int n_in,
                              void* d_out, int out_size, void* d_ws, size_t ws_size,
                              hipStream_t stream)
{
  const float* x      = (const float*)d_in[0];
  const float* ln_w   = (const float*)d_in[1];
  const float* ln_b   = (const float*)d_in[2];
  const float* inW    = (const float*)d_in[3];
  const float* convW  = (const float*)d_in[4];
  const float* convB  = (const float*)d_in[5];
  const float* xprojW = (const float*)d_in[6];
  const float* dtW    = (const float*)d_in[7];
  const float* dtB    = (const float*)d_in[8];
  const float* A_log  = (const float*)d_in[9];
  const float* Dskip  = (const float*)d_in[10];
  const float* outW   = (const float*)d_in[11];
  const float* projW  = (const float*)d_in[12];
  const float* projB  = (const float*)d_in[13];
  const float* skip   = (const float*)d_in[14];
  float* out = (float*)d_out;

  const size_t BL = (size_t)B_SZ * LSEQ;   // 8192
  char* p = (char*)d_ws;
  unsigned short* xn_bf = (unsigned short*)p;  p += BL*256*2;
  unsigned short* xz_bf = (unsigned short*)p;  p += BL*1024*2;
  unsigned short* xc_bf = (unsigned short*)p;  p += BL*512*2;
  float* dbc    = (float*)p;                   p += BL*48*4;
  unsigned short* delta_bf = (unsigned short*)p; p += BL*512*2;
  unsigned short* hloc   = (unsigned short*)p; p += (size_t)NCH*B_SZ*512*16*2;
  unsigned short* henter = (unsigned short*)p; p += (size_t)NCH*B_SZ*512*16*2;
  float* Ssum   = (float*)p;                   p += (size_t)NCH*B_SZ*512*4;
  unsigned short* y_bf = (unsigned short*)p;   p += BL*512*2;
  unsigned short* inW_bf  = (unsigned short*)p; p += 1024*256*2;
  unsigned short* outW_bf = (unsigned short*)p; p += 256*512*2;
  unsigned short* projW_bf= (unsigned short*)p; p += 256*256*2;
  unsigned short* xprojW_bf=(unsigned short*)p; p += 48*512*2;
  float* Ar_tab = (float*)p;                   p += 512*16*4;
  float* Eg     = (float*)p;                   p += (size_t)NG*B_SZ*8192*4;
  float* Vg     = (float*)p;                   p += (size_t)NG*B_SZ*8192*4;
  // overlays (disjoint lifetimes):
  unsigned short* xm_bf  = hloc;    // born after scanB (hloc dead after scanmidC)
  unsigned short* xn2_bf = xn_bf;   // xn_bf dead after in_proj

  prep_kernel<<<2048 + 480, 256, 0, stream>>>(
      x, ln_w, ln_b, xn_bf, inW, inW_bf, outW, outW_bf,
      projW, projW_bf, xprojW, xprojW_bf, A_log, Ar_tab);

  gemm_mfma<128,128,EPI_NONE><<<dim3(BL/128, 1024/128), 256, 0, stream>>>(
      xn_bf, inW_bf, xz_bf, (int)BL, 1024, 256, nullptr, nullptr, nullptr);

  conv_silu_kernel<<<(B_SZ*LSEQ*128)/256, 256, 0, stream>>>(xz_bf, convW, convB, xc_bf);

  gemm_mfma48<<<BL/64, 256, 0, stream>>>(xc_bf, xprojW_bf, dbc, 512);

  dtproj2_kernel<<<BL/DROWS, 256, 0, stream>>>(dbc, dtW, dtB, delta_bf);

  scanA_kernel<<<(B_SZ*NCH*512*2)/256, 256, 0, stream>>>(
      delta_bf, xc_bf, dbc, Ar_tab, hloc, Ssum);
  scanmidA_kernel<<<B_SZ*NG*32, 256, 0, stream>>>(hloc, Ssum, Ar_tab, Eg, Vg);
  scanmidC_kernel<<<B_SZ*NG*32, 256, 0, stream>>>(hloc, Ssum, Ar_tab, Eg, Vg, henter);
  scanB_kernel<<<(B_SZ*NCH*512*2)/256, 256, 0, stream>>>(
      delta_bf, xc_bf, dbc, Ar_tab, henter, Dskip, xz_bf, y_bf);

  gemm_mfma<64,64,EPI_SKIPX><<<dim3(BL/64, 256/64), 256, 0, stream>>>(
      y_bf, outW_bf, xm_bf, (int)BL, 256, 512, x, skip, nullptr);

  ln_bf16_kernel<<<BL/4, 256, 0, stream>>>(xm_bf, ln_w, ln_b, xn2_bf);

  gemm_mfma<64,64,EPI_BIAS><<<dim3(BL/64, 256/64), 256, 0, stream>>>(
      xn2_bf, projW_bf, out, (int)BL, 256, 256, nullptr, nullptr, projB);
}